// Round 9
// baseline (819.159 us; speedup 1.0000x reference)
//
#include <hip/hip_runtime.h>
#include <hip/hip_bf16.h>

typedef __hip_bfloat16 bf16;
typedef __attribute__((ext_vector_type(8))) short bfrag8;
typedef __attribute__((ext_vector_type(4))) float f32x4;

#define N_LIG 4096
#define N_REC 8192
#define E_LIG 65536
#define E_REC 262144
#define F_LIGc 15
#define F_RECc 27

__device__ __forceinline__ float ldkv(const float* p, size_t i) { return p[i]; }
__device__ __forceinline__ float ldkv(const bf16* p, size_t i) { return __bfloat162float(p[i]); }
__device__ __forceinline__ short bfbits(float x) {
    bf16 b = __float2bfloat16(x);
    return *(short*)&b;
}

__constant__ float c_inv_sigma[15] = {
    1.0f, 0.6666666667f, 0.4444444444f, 0.2962962963f, 0.1975308642f,
    0.1316872428f, 0.08779149520f, 0.05852766346f, 0.03901844231f,
    0.02601229487f, 0.01734152992f, 0.01156101994f, 0.007707346628f,
    0.005138231085f, 0.003425487390f};

__device__ __forceinline__ float wave_sum(float v) {
    #pragma unroll
    for (int o = 32; o > 0; o >>= 1) v += __shfl_xor(v, o, 64);
    return v;
}
__device__ __forceinline__ float quad_max(float v) {
    v = fmaxf(v, __shfl_xor(v, 1)); v = fmaxf(v, __shfl_xor(v, 2));
    v = fmaxf(v, __shfl_xor(v, 4)); v = fmaxf(v, __shfl_xor(v, 8));
    return v;
}
__device__ __forceinline__ float quad_sum(float v) {
    v += __shfl_xor(v, 1); v += __shfl_xor(v, 2);
    v += __shfl_xor(v, 4); v += __shfl_xor(v, 8);
    return v;
}

__global__ void zero_kernel(float* __restrict__ p, int n) {
    int i = blockIdx.x * blockDim.x + threadIdx.x;
    if (i < n) p[i] = 0.f;
}

// ============ MFMA edge kernel v2: xb/h1f LDS aliased, 4 blocks/CU ============
// GEMM1 accumulates all 4 m-tiles in registers so xb can be reused for h1f.
template <int F, int K1S>
__global__ __launch_bounds__(256, 4) void edge_mfma(
    const float* __restrict__ coords, const float* __restrict__ h,
    const int* __restrict__ src, const int* __restrict__ dst,
    const float* __restrict__ efeat,
    const float* __restrict__ w1, const float* __restrict__ b1,
    const float* __restrict__ g, const float* __restrict__ bt,
    const float* __restrict__ w2, const float* __restrict__ b2,
    const float* __restrict__ cw1, const float* __restrict__ cb1,
    const float* __restrict__ cw2, const float* __restrict__ cb2,
    float* __restrict__ aggr, float* __restrict__ cnt, float* __restrict__ xacc)
{
    constexpr int IN = 143 + F;
    constexpr int KP = K1S * 32 + 8;
    constexpr int XBYTES = 64 * KP * 2;   // >= 64*68*4 for both F=15 (21504) and F=27 (25600)
    static_assert(XBYTES >= 64 * 68 * 4, "h1f alias must fit in xb");
    __shared__ __align__(16) char smem[XBYTES];
    __shared__ __align__(16) unsigned short h1b[64 * 72];
    __shared__ float sums[256], sums2[256];
    __shared__ float stat_m[64], stat_r[64];
    __shared__ float coefp[4][64];
    __shared__ int dsts[64];
    __shared__ float xr_s[64][3], d2s[64];
    unsigned short* xb   = (unsigned short*)smem;
    float*          h1f  = (float*)smem;            // alias: valid after GEMM1 regs+barrier
    unsigned short* msgb = (unsigned short*)smem;   // alias: valid after h1b built

    const int t  = threadIdx.x;
    const int wv = t >> 6;
    const int L  = t & 63;
    const int lm = L & 15;
    const int qd = L >> 4;
    const int e0 = blockIdx.x * 64;
    const int n  = wv * 16 + lm;

    bfrag8 w1f[K1S], w2f[2], c1f[2];
    #pragma unroll
    for (int kk = 0; kk < K1S; ++kk)
        #pragma unroll
        for (int j = 0; j < 8; ++j) {
            int k = kk * 32 + qd * 8 + j;
            w1f[kk][j] = (k < IN) ? bfbits(w1[k * 64 + n]) : (short)0;
        }
    #pragma unroll
    for (int kk = 0; kk < 2; ++kk)
        #pragma unroll
        for (int j = 0; j < 8; ++j) {
            int k = kk * 32 + qd * 8 + j;
            w2f[kk][j] = bfbits(w2[k * 64 + n]);
            c1f[kk][j] = bfbits(cw1[k * 64 + n]);
        }
    const float b1n = b1[n], b2n = b2[n], cb1n = cb1[n], cw2n = cw2[n];

    if (t < 64) {
        int e = e0 + t;
        int s = src[e], d = dst[e];
        dsts[t] = d;
        float x0 = coords[s * 3 + 0] - coords[d * 3 + 0];
        float x1 = coords[s * 3 + 1] - coords[d * 3 + 1];
        float x2 = coords[s * 3 + 2] - coords[d * 3 + 2];
        xr_s[t][0] = x0; xr_s[t][1] = x1; xr_s[t][2] = x2;
        d2s[t] = x0 * x0 + x1 * x1 + x2 * x2;
    }

    for (int p = 0; p < 16; ++p) {
        int e = (t >> 6) + 4 * p;
        int ge = e0 + e;
        int s = src[ge], d = dst[ge];
        int j = t & 63;
        xb[e * KP + j]      = bfbits(h[(size_t)s * 64 + j]);
        xb[e * KP + 64 + j] = bfbits(h[(size_t)d * 64 + j]);
    }
    for (int idx = t; idx < 64 * F; idx += 256) {
        int e = idx / F, f = idx - e * F;
        xb[e * KP + 128 + f] = bfbits(efeat[(size_t)(e0 + e) * F + f]);
    }
    {
        constexpr int PER = K1S * 32 - IN;
        for (int idx = t; idx < 64 * PER; idx += 256) {
            int e = idx / PER, k = idx - e * PER;
            xb[e * KP + IN + k] = 0;
        }
    }
    __syncthreads();
    for (int idx = t; idx < 64 * 15; idx += 256) {
        int e = idx / 15, s5 = idx - e * 15;
        xb[e * KP + 128 + F + s5] = bfbits(__expf(-d2s[e] * c_inv_sigma[s5]));
    }
    __syncthreads();

    // ---- GEMM 1 into registers (xb stays read-only during MFMAs) ----
    f32x4 acc1[4];
    #pragma unroll
    for (int m = 0; m < 4; ++m) {
        f32x4 acc = {0.f, 0.f, 0.f, 0.f};
        #pragma unroll
        for (int kk = 0; kk < K1S; ++kk) {
            bfrag8 a = *(const bfrag8*)&xb[(m * 16 + lm) * KP + kk * 32 + qd * 8];
            acc = __builtin_amdgcn_mfma_f32_16x16x32_bf16(a, w1f[kk], acc, 0, 0, 0);
        }
        acc1[m] = acc;
    }
    __syncthreads();   // all xb reads complete -> safe to overwrite via h1f alias
    #pragma unroll
    for (int m = 0; m < 4; ++m)
        #pragma unroll
        for (int r = 0; r < 4; ++r) {
            int mr = m * 16 + qd * 4 + r;
            float v = acc1[m][r] + b1n;
            v = v > 0.f ? v : 0.01f * v;
            h1f[mr * 68 + n] = v;
        }
    __syncthreads();

    {
        int e = t >> 2, seg = (t & 3) * 16;
        float s1 = 0.f, s2 = 0.f;
        #pragma unroll
        for (int j = 0; j < 16; ++j) {
            float v = h1f[e * 68 + seg + j];
            s1 += v; s2 += v * v;
        }
        sums[t] = s1; sums2[t] = s2;
    }
    __syncthreads();
    if (t < 64) {
        float s1 = sums[4 * t] + sums[4 * t + 1] + sums[4 * t + 2] + sums[4 * t + 3];
        float s2 = sums2[4 * t] + sums2[4 * t + 1] + sums2[4 * t + 2] + sums2[4 * t + 3];
        float mean = s1 * (1.f / 64.f);
        float var = s2 * (1.f / 64.f) - mean * mean;
        stat_m[t] = mean;
        stat_r[t] = rsqrtf(fmaxf(var, 0.f) + 1e-5f);
    }
    __syncthreads();
    for (int idx = t; idx < 4096; idx += 256) {
        int e = idx >> 6, j = idx & 63;
        float v = (h1f[e * 68 + j] - stat_m[e]) * stat_r[e] * g[j] + bt[j];
        h1b[e * 72 + j] = bfbits(v);
    }
    __syncthreads();   // h1b ready; h1f dead -> msgb alias OK

    #pragma unroll
    for (int m = 0; m < 4; ++m) {
        f32x4 acc = {0.f, 0.f, 0.f, 0.f};
        #pragma unroll
        for (int kk = 0; kk < 2; ++kk) {
            bfrag8 a = *(const bfrag8*)&h1b[(m * 16 + lm) * 72 + kk * 32 + qd * 8];
            acc = __builtin_amdgcn_mfma_f32_16x16x32_bf16(a, w2f[kk], acc, 0, 0, 0);
        }
        #pragma unroll
        for (int r = 0; r < 4; ++r) {
            int mr = m * 16 + qd * 4 + r;
            float v = acc[r] + b2n;
            atomicAdd(&aggr[(size_t)dsts[mr] * 64 + n], v);
            msgb[mr * 72 + n] = bfbits(v);
        }
    }
    __syncthreads();

    #pragma unroll
    for (int m = 0; m < 4; ++m) {
        f32x4 acc = {0.f, 0.f, 0.f, 0.f};
        #pragma unroll
        for (int kk = 0; kk < 2; ++kk) {
            bfrag8 a = *(const bfrag8*)&msgb[(m * 16 + lm) * 72 + kk * 32 + qd * 8];
            acc = __builtin_amdgcn_mfma_f32_16x16x32_bf16(a, c1f[kk], acc, 0, 0, 0);
        }
        #pragma unroll
        for (int r = 0; r < 4; ++r) {
            float v = acc[r] + cb1n;
            v = v > 0.f ? v : 0.01f * v;
            v *= cw2n;
            v += __shfl_xor(v, 1);
            v += __shfl_xor(v, 2);
            v += __shfl_xor(v, 4);
            v += __shfl_xor(v, 8);
            if (lm == 0) coefp[wv][m * 16 + qd * 4 + r] = v;
        }
    }
    __syncthreads();
    if (t < 64) {
        float coef = coefp[0][t] + coefp[1][t] + coefp[2][t] + coefp[3][t] + cb2[0];
        int d = dsts[t];
        atomicAdd(&cnt[d], 1.f);
        atomicAdd(&xacc[d * 3 + 0], xr_s[t][0] * coef);
        atomicAdd(&xacc[d * 3 + 1], xr_s[t][1] * coef);
        atomicAdd(&xacc[d * 3 + 2], xr_s[t][2] * coef);
    }
}

// ---------------- k/v projection (bf16 out) ----------------
__global__ __launch_bounds__(64) void linear64_kernel(
    const float* __restrict__ h, const float* __restrict__ w,
    bf16* __restrict__ out, int do_lrelu)
{
    int node = blockIdx.x;
    int j = threadIdx.x;
    __shared__ float x[64];
    x[j] = h[(size_t)node * 64 + j];
    __syncthreads();
    float acc = 0.f;
    #pragma unroll 8
    for (int i = 0; i < 64; ++i) acc += x[i] * w[i * 64 + j];
    if (do_lrelu) acc = acc > 0.f ? acc : 0.01f * acc;
    out[(size_t)node * 64 + j] = __float2bfloat16(acc);
}

// ---------------- u8 mask build ----------------
__global__ __launch_bounds__(256) void build_masks(
    const float* __restrict__ mask, unsigned char* __restrict__ m8,
    unsigned char* __restrict__ m8T, int R, int C)
{
    __shared__ __align__(16) unsigned char tl[64 * 80];
    int r0 = blockIdx.y * 64, c0 = blockIdx.x * 64;
    int t = threadIdx.x;
    int cs = (t & 15) * 4;
    #pragma unroll
    for (int rr = 0; rr < 4; ++rr) {
        int r = (t >> 4) + rr * 16;
        unsigned b0 = (mask[(size_t)(r0 + r) * C + c0 + cs + 0] != 0.f);
        unsigned b1 = (mask[(size_t)(r0 + r) * C + c0 + cs + 1] != 0.f);
        unsigned b2 = (mask[(size_t)(r0 + r) * C + c0 + cs + 2] != 0.f);
        unsigned b3 = (mask[(size_t)(r0 + r) * C + c0 + cs + 3] != 0.f);
        *(unsigned*)&m8[(size_t)(r0 + r) * C + c0 + cs] = b0 | (b1 << 8) | (b2 << 16) | (b3 << 24);
        tl[(cs + 0) * 80 + r] = (unsigned char)b0;
        tl[(cs + 1) * 80 + r] = (unsigned char)b1;
        tl[(cs + 2) * 80 + r] = (unsigned char)b2;
        tl[(cs + 3) * 80 + r] = (unsigned char)b3;
    }
    __syncthreads();
    {
        int c = t >> 2, rs = (t & 3) * 16;
        *(uint4*)&m8T[(size_t)(c0 + c) * R + r0 + rs] = *(const uint4*)&tl[c * 80 + rs];
    }
}

// ============ MFMA flash attention, both directions in one launch ============
template <int MMODE>  // 0: u8 mask, 1: strided f32 mask
__global__ __launch_bounds__(256) void attn_mfma(
    int nb1,
    const float* __restrict__ h1, const float* __restrict__ qw1,
    const bf16* __restrict__ k1, const bf16* __restrict__ v1,
    const unsigned char* __restrict__ m81, const float* __restrict__ mf1, long mrs1, long mcs1,
    float* __restrict__ pO1, float* __restrict__ pM1, float* __restrict__ pL1,
    int nrows1, int ncols1, int nsplit1,
    const float* __restrict__ h2, const float* __restrict__ qw2,
    const bf16* __restrict__ k2, const bf16* __restrict__ v2,
    const unsigned char* __restrict__ m82, const float* __restrict__ mf2, long mrs2, long mcs2,
    float* __restrict__ pO2, float* __restrict__ pM2, float* __restrict__ pL2,
    int nrows2, int ncols2, int nsplit2)
{
    const float *h, *qw, *mf;
    const bf16 *kkp, *vvp;
    const unsigned char* m8;
    long mrs, mcs;
    float *pO, *pM, *pL;
    int n_rows, n_cols, nsplit, bid;
    if ((int)blockIdx.x < nb1) {
        h = h1; qw = qw1; kkp = k1; vvp = v1; m8 = m81; mf = mf1; mrs = mrs1; mcs = mcs1;
        pO = pO1; pM = pM1; pL = pL1; n_rows = nrows1; n_cols = ncols1; nsplit = nsplit1;
        bid = blockIdx.x;
    } else {
        h = h2; qw = qw2; kkp = k2; vvp = v2; m8 = m82; mf = mf2; mrs = mrs2; mcs = mcs2;
        pO = pO2; pM = pM2; pL = pL2; n_rows = nrows2; n_cols = ncols2; nsplit = nsplit2;
        bid = blockIdx.x - nb1;
    }

    const int t  = threadIdx.x;
    const int wv = t >> 6;
    const int lm = t & 15;
    const int qd = (t & 63) >> 4;
    const int rb = bid / nsplit;
    const int sp = bid - rb * nsplit;
    const int r0 = rb * 64;
    const int cols_per = n_cols / nsplit;
    const int c_begin = sp * cols_per;

    __shared__ __align__(16) unsigned short qb[64 * 72];
    __shared__ __align__(16) unsigned short kvb[64 * 72];
    __shared__ __align__(16) unsigned short pb[64 * 72];
    __shared__ __align__(16) unsigned char mt[4096];

    {
        int r = t >> 3, seg = (t & 7) * 8;
        #pragma unroll
        for (int u = 0; u < 2; ++u) {
            int rr = r + 32 * u;
            const float* hp = h + (size_t)(r0 + rr) * 64 + seg;
            unsigned short tmp[8];
            #pragma unroll
            for (int j = 0; j < 8; ++j) tmp[j] = bfbits(hp[j]);
            *(uint4*)&qb[rr * 72 + seg] = *(uint4*)tmp;
            const float* qp = qw + (size_t)rr * 64 + seg;
            #pragma unroll
            for (int j = 0; j < 8; ++j) kvb[(seg + j) * 72 + rr] = bfbits(qp[j]);
        }
    }
    __syncthreads();
    {
        bfrag8 a0 = *(const bfrag8*)&qb[(wv * 16 + lm) * 72 + qd * 8];
        bfrag8 a1 = *(const bfrag8*)&qb[(wv * 16 + lm) * 72 + 32 + qd * 8];
        #pragma unroll
        for (int ns = 0; ns < 4; ++ns) {
            f32x4 acc = {0.f, 0.f, 0.f, 0.f};
            bfrag8 b0 = *(const bfrag8*)&kvb[(ns * 16 + lm) * 72 + qd * 8];
            bfrag8 b1 = *(const bfrag8*)&kvb[(ns * 16 + lm) * 72 + 32 + qd * 8];
            acc = __builtin_amdgcn_mfma_f32_16x16x32_bf16(a0, b0, acc, 0, 0, 0);
            acc = __builtin_amdgcn_mfma_f32_16x16x32_bf16(a1, b1, acc, 0, 0, 0);
            #pragma unroll
            for (int r = 0; r < 4; ++r) {
                float v = acc[r];
                v = v > 0.f ? v : 0.01f * v;
                pb[(wv * 16 + qd * 4 + r) * 72 + ns * 16 + lm] = bfbits(v);
            }
        }
    }
    __syncthreads();
    for (int idx = t; idx < 64 * 9; idx += 256) {
        int r = idx / 9, seg = (idx - r * 9) * 8;
        if (seg < 64) *(uint4*)&qb[r * 72 + seg] = *(const uint4*)&pb[r * 72 + seg];
    }
    __syncthreads();

    float rm[4], rl[4];
    #pragma unroll
    for (int r = 0; r < 4; ++r) { rm[r] = -1e30f; rl[r] = 0.f; }
    f32x4 o[4];
    #pragma unroll
    for (int ds = 0; ds < 4; ++ds) o[ds] = (f32x4){0.f, 0.f, 0.f, 0.f};

    for (int c0 = c_begin; c0 < c_begin + cols_per; c0 += 64) {
        {
            int c = t >> 3, seg = (t & 7) * 8;
            #pragma unroll
            for (int u = 0; u < 2; ++u) {
                int cc = c + 32 * u;
                *(uint4*)&kvb[cc * 72 + seg] =
                    *(const uint4*)(kkp + (size_t)(c0 + cc) * 64 + seg);
            }
        }
        if (MMODE == 0) {
            int r = t >> 2, seg = (t & 3) * 16;
            *(uint4*)&mt[r * 64 + seg] =
                *(const uint4*)&m8[(size_t)(r0 + r) * n_cols + c0 + seg];
        } else {
            #pragma unroll
            for (int u = 0; u < 16; ++u) {
                int i = t + 256 * u;
                int r = i >> 6, c = i & 63;
                mt[r * 64 + c] = (unsigned char)(
                    mf[(size_t)(r0 + r) * mrs + (size_t)(c0 + c) * mcs] != 0.f);
            }
        }
        __syncthreads();

        f32x4 s[4];
        {
            bfrag8 a0 = *(const bfrag8*)&qb[(wv * 16 + lm) * 72 + qd * 8];
            bfrag8 a1 = *(const bfrag8*)&qb[(wv * 16 + lm) * 72 + 32 + qd * 8];
            #pragma unroll
            for (int ns = 0; ns < 4; ++ns) {
                f32x4 acc = {0.f, 0.f, 0.f, 0.f};
                bfrag8 b0 = *(const bfrag8*)&kvb[(ns * 16 + lm) * 72 + qd * 8];
                bfrag8 b1 = *(const bfrag8*)&kvb[(ns * 16 + lm) * 72 + 32 + qd * 8];
                acc = __builtin_amdgcn_mfma_f32_16x16x32_bf16(a0, b0, acc, 0, 0, 0);
                acc = __builtin_amdgcn_mfma_f32_16x16x32_bf16(a1, b1, acc, 0, 0, 0);
                s[ns] = acc;
            }
        }
        float alpha[4];
        #pragma unroll
        for (int r = 0; r < 4; ++r) {
            int rloc = wv * 16 + qd * 4 + r;
            float v0 = mt[rloc * 64 +  0 + lm] ? s[0][r] : -1000.f;
            float v1 = mt[rloc * 64 + 16 + lm] ? s[1][r] : -1000.f;
            float v2 = mt[rloc * 64 + 32 + lm] ? s[2][r] : -1000.f;
            float v3 = mt[rloc * 64 + 48 + lm] ? s[3][r] : -1000.f;
            float mx = quad_max(fmaxf(fmaxf(v0, v1), fmaxf(v2, v3)));
            float mn = fmaxf(rm[r], mx);
            float al = __expf(rm[r] - mn);
            rm[r] = mn; alpha[r] = al;
            float p0 = __expf(v0 - mn), p1 = __expf(v1 - mn);
            float p2 = __expf(v2 - mn), p3 = __expf(v3 - mn);
            pb[rloc * 72 +  0 + lm] = bfbits(p0);
            pb[rloc * 72 + 16 + lm] = bfbits(p1);
            pb[rloc * 72 + 32 + lm] = bfbits(p2);
            pb[rloc * 72 + 48 + lm] = bfbits(p3);
            float ls = quad_sum(p0 + p1 + p2 + p3);
            rl[r] = rl[r] * al + ls;
        }
        #pragma unroll
        for (int ds = 0; ds < 4; ++ds)
            #pragma unroll
            for (int r = 0; r < 4; ++r) o[ds][r] *= alpha[r];
        __syncthreads();

        {
            int c = t >> 3, seg = (t & 7) * 8;
            #pragma unroll
            for (int u = 0; u < 2; ++u) {
                int cc = c + 32 * u;
                uint4 raw = *(const uint4*)(vvp + (size_t)(c0 + cc) * 64 + seg);
                unsigned short* pr = (unsigned short*)&raw;
                #pragma unroll
                for (int j = 0; j < 8; ++j) kvb[(seg + j) * 72 + cc] = pr[j];
            }
        }
        __syncthreads();

        {
            bfrag8 a0 = *(const bfrag8*)&pb[(wv * 16 + lm) * 72 + qd * 8];
            bfrag8 a1 = *(const bfrag8*)&pb[(wv * 16 + lm) * 72 + 32 + qd * 8];
            #pragma unroll
            for (int ds = 0; ds < 4; ++ds) {
                bfrag8 b0 = *(const bfrag8*)&kvb[(ds * 16 + lm) * 72 + qd * 8];
                bfrag8 b1 = *(const bfrag8*)&kvb[(ds * 16 + lm) * 72 + 32 + qd * 8];
                o[ds] = __builtin_amdgcn_mfma_f32_16x16x32_bf16(a0, b0, o[ds], 0, 0, 0);
                o[ds] = __builtin_amdgcn_mfma_f32_16x16x32_bf16(a1, b1, o[ds], 0, 0, 0);
            }
        }
        __syncthreads();
    }

    #pragma unroll
    for (int ds = 0; ds < 4; ++ds)
        #pragma unroll
        for (int r = 0; r < 4; ++r) {
            int row = r0 + wv * 16 + qd * 4 + r;
            pO[((size_t)sp * n_rows + row) * 64 + ds * 16 + lm] = o[ds][r];
        }
    if (lm == 0) {
        #pragma unroll
        for (int r = 0; r < 4; ++r) {
            int row = r0 + wv * 16 + qd * 4 + r;
            pM[(size_t)sp * n_rows + row] = rm[r];
            pL[(size_t)sp * n_rows + row] = rl[r];
        }
    }
}

// ---------------- merge split partials ----------------
__global__ __launch_bounds__(64) void attn_merge(
    const float* __restrict__ pO, const float* __restrict__ pM, const float* __restrict__ pL,
    float* __restrict__ out, int n_rows, int nsplit)
{
    int r = blockIdx.x;
    int d = threadIdx.x;
    float mstar = -1e30f;
    for (int s = 0; s < nsplit; ++s) mstar = fmaxf(mstar, pM[(size_t)s * n_rows + r]);
    float L = 0.f, O = 0.f;
    for (int s = 0; s < nsplit; ++s) {
        float w = __expf(pM[(size_t)s * n_rows + r] - mstar);
        L += pL[(size_t)s * n_rows + r] * w;
        O += pO[((size_t)s * n_rows + r) * 64 + d] * w;
    }
    out[(size_t)r * 64 + d] = O / L;
}

// ---------------- per-row attention (tier-2 fallback) ----------------
__global__ __launch_bounds__(256) void attn_row_kernel(
    const float* __restrict__ h, const float* __restrict__ qw,
    const bf16* __restrict__ k, const bf16* __restrict__ v,
    const float* __restrict__ mask, long mrs, long mcs,
    float* __restrict__ out, int n_cols)
{
    int row = blockIdx.x;
    int tid = threadIdx.x;
    extern __shared__ float sc[];
    __shared__ float hrow[64];
    __shared__ float qrow[64];
    __shared__ float red[4];
    __shared__ float opart[4][64];

    if (tid < 64) hrow[tid] = h[(size_t)row * 64 + tid];
    __syncthreads();
    if (tid < 64) {
        float a = 0.f;
        #pragma unroll 8
        for (int i = 0; i < 64; ++i) a += hrow[i] * qw[i * 64 + tid];
        qrow[tid] = a > 0.f ? a : 0.01f * a;
    }
    __syncthreads();

    float lmax = -1e30f;
    for (int c = tid; c < n_cols; c += 256) {
        const bf16* kr = k + (size_t)c * 64;
        float s = 0.f;
        #pragma unroll 8
        for (int i = 0; i < 64; ++i) s += qrow[i] * ldkv(kr, i);
        float m = mask[(size_t)row * mrs + (size_t)c * mcs];
        s = m * s - 1000.f * (1.f - m);
        sc[c] = s;
        lmax = fmaxf(lmax, s);
    }
    #pragma unroll
    for (int o = 32; o > 0; o >>= 1) lmax = fmaxf(lmax, __shfl_xor(lmax, o, 64));
    int wid = tid >> 6;
    if ((tid & 63) == 0) red[wid] = lmax;
    __syncthreads();
    float bmax = fmaxf(fmaxf(red[0], red[1]), fmaxf(red[2], red[3]));
    __syncthreads();

    float lsum = 0.f;
    for (int c = tid; c < n_cols; c += 256) {
        float e = __expf(sc[c] - bmax);
        sc[c] = e;
        lsum += e;
    }
    lsum = wave_sum(lsum);
    if ((tid & 63) == 0) red[wid] = lsum;
    __syncthreads();
    float inv = 1.f / (red[0] + red[1] + red[2] + red[3]);

    int dd = tid & 63;
    float o = 0.f;
    for (int c = wid; c < n_cols; c += 4) o += sc[c] * ldkv(v, (size_t)c * 64 + dd);
    opart[wid][dd] = o;
    __syncthreads();
    if (wid == 0)
        out[(size_t)row * 64 + dd] =
            (opart[0][dd] + opart[1][dd] + opart[2][dd] + opart[3][dd]) * inv;
}

// ---------------- node feature update ----------------
__global__ __launch_bounds__(64) void node_kernel(
    const float* __restrict__ h, const float* __restrict__ aggr,
    const float* __restrict__ cnt, const float* att,  // aliases h_out
    const float* __restrict__ orig_h,
    const float* __restrict__ w1, const float* __restrict__ b1,
    const float* __restrict__ g, const float* __restrict__ bt,
    const float* __restrict__ w2, const float* __restrict__ b2,
    float* h_out)
{
    int node = blockIdx.x;
    int j = threadIdx.x;
    __shared__ float xin[256];
    __shared__ float hbuf[64];
    float invc = 1.f / fmaxf(cnt[node], 1.f);
    float hv = h[(size_t)node * 64 + j];
    xin[j]       = hv;
    xin[64 + j]  = aggr[(size_t)node * 64 + j] * invc;
    xin[128 + j] = att[(size_t)node * 64 + j];
    xin[192 + j] = orig_h[(size_t)node * 64 + j];
    __syncthreads();
    float acc = b1[j];
    #pragma unroll 4
    for (int i = 0; i < 256; ++i) acc += xin[i] * w1[i * 64 + j];
    acc = acc > 0.f ? acc : 0.01f * acc;
    float mean = wave_sum(acc) * (1.f / 64.f);
    float cv = acc - mean;
    float var = wave_sum(cv * cv) * (1.f / 64.f);
    float y = cv * rsqrtf(var + 1e-5f) * g[j] + bt[j];
    hbuf[j] = y;
    __syncthreads();
    float o = b2[j];
    #pragma unroll 8
    for (int i = 0; i < 64; ++i) o += hbuf[i] * w2[i * 64 + j];
    h_out[(size_t)node * 64 + j] = 0.5f * o + 0.5f * hv;
}

// ---------------- coordinate output ----------------
__global__ void coord_kernel(
    const float* __restrict__ orig, const float* __restrict__ coords,
    const float* __restrict__ xacc, const float* __restrict__ cnt,
    float* __restrict__ out, int n3)
{
    int i = blockIdx.x * blockDim.x + threadIdx.x;
    if (i >= n3) return;
    int node = i / 3;
    float invc = 1.f / fmaxf(cnt[node], 1.f);
    out[i] = 0.25f * orig[i] + 0.75f * coords[i] + xacc[i] * invc;
}

extern "C" void kernel_launch(void* const* d_in, const int* in_sizes, int n_in,
                              void* d_out, int out_size, void* d_ws, size_t ws_size,
                              hipStream_t stream)
{
    const float* coords_lig      = (const float*)d_in[0];
    const float* h_lig           = (const float*)d_in[1];
    const float* orig_h_lig      = (const float*)d_in[2];
    const float* orig_coords_lig = (const float*)d_in[3];
    const float* coords_rec      = (const float*)d_in[4];
    const float* h_rec           = (const float*)d_in[5];
    const float* orig_h_rec      = (const float*)d_in[6];
    const float* orig_coords_rec = (const float*)d_in[7];
    const int* lig_src   = (const int*)d_in[8];
    const int* lig_dst   = (const int*)d_in[9];
    const float* lig_efeat = (const float*)d_in[10];
    const int* rec_src   = (const int*)d_in[11];
    const int* rec_dst   = (const int*)d_in[12];
    const float* rec_efeat = (const float*)d_in[13];
    const float* mask      = (const float*)d_in[14];
    const float *lig_em_w1 = (const float*)d_in[15], *lig_em_b1 = (const float*)d_in[16];
    const float *lig_em_g  = (const float*)d_in[17], *lig_em_bt = (const float*)d_in[18];
    const float *lig_em_w2 = (const float*)d_in[19], *lig_em_b2 = (const float*)d_in[20];
    const float *rec_em_w1 = (const float*)d_in[21], *rec_em_b1 = (const float*)d_in[22];
    const float *rec_em_g  = (const float*)d_in[23], *rec_em_bt = (const float*)d_in[24];
    const float *rec_em_w2 = (const float*)d_in[25], *rec_em_b2 = (const float*)d_in[26];
    const float *lig_cm_w1 = (const float*)d_in[27], *lig_cm_b1 = (const float*)d_in[28];
    const float *lig_cm_w2 = (const float*)d_in[29], *lig_cm_b2 = (const float*)d_in[30];
    const float *rec_cm_w1 = (const float*)d_in[31], *rec_cm_b1 = (const float*)d_in[32];
    const float *rec_cm_w2 = (const float*)d_in[33], *rec_cm_b2 = (const float*)d_in[34];
    const float *q_lig_w = (const float*)d_in[35], *k_lig_w = (const float*)d_in[36];
    const float *v_lig_w = (const float*)d_in[37], *q_rec_w = (const float*)d_in[38];
    const float *k_rec_w = (const float*)d_in[39], *v_rec_w = (const float*)d_in[40];
    const float *lig_nm_w1 = (const float*)d_in[41], *lig_nm_b1 = (const float*)d_in[42];
    const float *lig_nm_g  = (const float*)d_in[43], *lig_nm_bt = (const float*)d_in[44];
    const float *lig_nm_w2 = (const float*)d_in[45], *lig_nm_b2 = (const float*)d_in[46];
    const float *rec_nm_w1 = (const float*)d_in[47], *rec_nm_b1 = (const float*)d_in[48];
    const float *rec_nm_g  = (const float*)d_in[49], *rec_nm_bt = (const float*)d_in[50];
    const float *rec_nm_w2 = (const float*)d_in[51], *rec_nm_b2 = (const float*)d_in[52];

    char* wsb = (char*)d_ws;
    float* aggr_l = (float*)(wsb + 16);
    float* aggr_r = aggr_l + (size_t)N_LIG * 64;
    float* cnt_l  = aggr_r + (size_t)N_REC * 64;
    float* cnt_r  = cnt_l + N_LIG;
    float* xacc_l = cnt_r + N_REC;
    float* xacc_r = xacc_l + (size_t)N_LIG * 3;
    const size_t zero_floats =
        (size_t)N_LIG * 64 + (size_t)N_REC * 64 + N_LIG + N_REC + N_LIG * 3 + N_REC * 3;
    const size_t core_b = 16 + zero_floats * 4;
    const size_t kv_b = (size_t)(N_LIG + N_REC) * 64 * 2 * 2;   // bf16 k+v both graphs
    const size_t part_b = ((size_t)4 * N_LIG * 64 + (size_t)2 * N_REC * 64) * 4
                        + ((size_t)4 * N_LIG + (size_t)2 * N_REC) * 2 * 4;
    const size_t m8_b = (size_t)N_LIG * N_REC;

    int tier;
    if (ws_size >= core_b + kv_b + part_b + 2 * m8_b) tier = 0;
    else if (ws_size >= core_b + kv_b + part_b) tier = 1;
    else tier = 2;

    char* kv_base = wsb + core_b;
    bf16* kb_l = (bf16*)kv_base;
    bf16* vb_l = kb_l + (size_t)N_LIG * 64;
    bf16* kb_r = vb_l + (size_t)N_LIG * 64;
    bf16* vb_r = kb_r + (size_t)N_REC * 64;
    float* pO1 = (float*)(kv_base + kv_b);
    float* pO2 = pO1 + (size_t)4 * N_LIG * 64;
    float* pM1 = pO2 + (size_t)2 * N_REC * 64;
    float* pL1 = pM1 + (size_t)4 * N_LIG;
    float* pM2 = pL1 + (size_t)4 * N_LIG;
    float* pL2 = pM2 + (size_t)2 * N_REC;
    unsigned char* m8  = (unsigned char*)(kv_base + kv_b + part_b);
    unsigned char* m8T = m8 + m8_b;

    float* out = (float*)d_out;
    float* x_lig_o = out;
    float* h_lig_o = out + 12288;
    float* x_rec_o = out + 274432;
    float* h_rec_o = out + 299008;

    zero_kernel<<<((int)zero_floats + 255) / 256, 256, 0, stream>>>(aggr_l, (int)zero_floats);

    // k/v projections (bf16)
    linear64_kernel<<<N_LIG, 64, 0, stream>>>(h_lig, k_lig_w, kb_l, 1);
    linear64_kernel<<<N_LIG, 64, 0, stream>>>(h_lig, v_lig_w, vb_l, 0);
    linear64_kernel<<<N_REC, 64, 0, stream>>>(h_rec, k_rec_w, kb_r, 1);
    linear64_kernel<<<N_REC, 64, 0, stream>>>(h_rec, v_rec_w, vb_r, 0);

    // MFMA edge kernels
    edge_mfma<F_LIGc, 5><<<E_LIG / 64, 256, 0, stream>>>(
        coords_lig, h_lig, lig_src, lig_dst, lig_efeat,
        lig_em_w1, lig_em_b1, lig_em_g, lig_em_bt, lig_em_w2, lig_em_b2,
        lig_cm_w1, lig_cm_b1, lig_cm_w2, lig_cm_b2,
        aggr_l, cnt_l, xacc_l);
    edge_mfma<F_RECc, 6><<<E_REC / 64, 256, 0, stream>>>(
        coords_rec, h_rec, rec_src, rec_dst, rec_efeat,
        rec_em_w1, rec_em_b1, rec_em_g, rec_em_bt, rec_em_w2, rec_em_b2,
        rec_cm_w1, rec_cm_b1, rec_cm_w2, rec_cm_b2,
        aggr_r, cnt_r, xacc_r);

    // attention (both directions in one launch)
    const int nb1 = (N_LIG / 64) * 4;
    const int nb2 = (N_REC / 64) * 2;
    if (tier <= 1) {
        if (tier == 0) {
            dim3 bg(N_REC / 64, N_LIG / 64);
            build_masks<<<bg, 256, 0, stream>>>(mask, m8, m8T, N_LIG, N_REC);
            attn_mfma<0><<<nb1 + nb2, 256, 0, stream>>>(
                nb1,
                h_lig, q_lig_w, kb_r, vb_r, m8, mask, 0L, 0L,
                pO1, pM1, pL1, N_LIG, N_REC, 4,
                h_rec, q_rec_w, kb_l, vb_l, m8T, mask, 0L, 0L,
                pO2, pM2, pL2, N_REC, N_LIG, 2);
        } else {
            attn_mfma<1><<<nb1 + nb2, 256, 0, stream>>>(
                nb1,
                h_lig, q_lig_w, kb_r, vb_r, (const unsigned char*)0, mask, (long)N_REC, 1L,
                pO1, pM1, pL1, N_LIG, N_REC, 4,
                h_rec, q_rec_w, kb_l, vb_l, (const unsigned char*)0, mask, 1L, (long)N_REC,
                pO2, pM2, pL2, N_REC, N_LIG, 2);
        }
        attn_merge<<<N_LIG, 64, 0, stream>>>(pO1, pM1, pL1, h_lig_o, N_LIG, 4);
        attn_merge<<<N_REC, 64, 0, stream>>>(pO2, pM2, pL2, h_rec_o, N_REC, 2);
    } else {
        attn_row_kernel<<<N_LIG, 256, N_REC * sizeof(float), stream>>>(
            h_lig, q_lig_w, kb_r, vb_r, mask, (long)N_REC, 1L, h_lig_o, N_REC);
        attn_row_kernel<<<N_REC, 256, N_LIG * sizeof(float), stream>>>(
            h_rec, q_rec_w, kb_l, vb_l, mask, 1L, (long)N_REC, h_rec_o, N_LIG);
    }

    // node updates
    node_kernel<<<N_LIG, 64, 0, stream>>>(
        h_lig, aggr_l, cnt_l, h_lig_o, orig_h_lig,
        lig_nm_w1, lig_nm_b1, lig_nm_g, lig_nm_bt, lig_nm_w2, lig_nm_b2, h_lig_o);
    node_kernel<<<N_REC, 64, 0, stream>>>(
        h_rec, aggr_r, cnt_r, h_rec_o, orig_h_rec,
        rec_nm_w1, rec_nm_b1, rec_nm_g, rec_nm_bt, rec_nm_w2, rec_nm_b2, h_rec_o);

    // coordinate outputs
    coord_kernel<<<(N_LIG * 3 + 255) / 256, 256, 0, stream>>>(
        orig_coords_lig, coords_lig, xacc_l, cnt_l, x_lig_o, N_LIG * 3);
    coord_kernel<<<(N_REC * 3 + 255) / 256, 256, 0, stream>>>(
        orig_coords_rec, coords_rec, xacc_r, cnt_r, x_rec_o, N_REC * 3);
}

// Round 10
// 803.624 us; speedup vs baseline: 1.0193x; 1.0193x over previous
//
#include <hip/hip_runtime.h>
#include <hip/hip_bf16.h>

typedef __hip_bfloat16 bf16;
typedef __attribute__((ext_vector_type(8))) short bfrag8;
typedef __attribute__((ext_vector_type(4))) float f32x4;

#define N_LIG 4096
#define N_REC 8192
#define E_LIG 65536
#define E_REC 262144
#define F_LIGc 15
#define F_RECc 27

__device__ __forceinline__ float ldkv(const float* p, size_t i) { return p[i]; }
__device__ __forceinline__ float ldkv(const bf16* p, size_t i) { return __bfloat162float(p[i]); }
__device__ __forceinline__ short bfbits(float x) {
    bf16 b = __float2bfloat16(x);
    return *(short*)&b;
}

__constant__ float c_inv_sigma[15] = {
    1.0f, 0.6666666667f, 0.4444444444f, 0.2962962963f, 0.1975308642f,
    0.1316872428f, 0.08779149520f, 0.05852766346f, 0.03901844231f,
    0.02601229487f, 0.01734152992f, 0.01156101994f, 0.007707346628f,
    0.005138231085f, 0.003425487390f};

__device__ __forceinline__ float wave_sum(float v) {
    #pragma unroll
    for (int o = 32; o > 0; o >>= 1) v += __shfl_xor(v, o, 64);
    return v;
}
__device__ __forceinline__ float quad_max(float v) {
    v = fmaxf(v, __shfl_xor(v, 1)); v = fmaxf(v, __shfl_xor(v, 2));
    v = fmaxf(v, __shfl_xor(v, 4)); v = fmaxf(v, __shfl_xor(v, 8));
    return v;
}
__device__ __forceinline__ float quad_sum(float v) {
    v += __shfl_xor(v, 1); v += __shfl_xor(v, 2);
    v += __shfl_xor(v, 4); v += __shfl_xor(v, 8);
    return v;
}

__global__ void zero_kernel(float* __restrict__ p, int n) {
    int i = blockIdx.x * blockDim.x + threadIdx.x;
    if (i < n) p[i] = 0.f;
}

// ---------------- counting sort: histogram / scan / scatter ----------------
__global__ void hist_kernel(const int* __restrict__ dst, int* __restrict__ counts, int ne) {
    int e = blockIdx.x * 256 + threadIdx.x;
    if (e < ne) atomicAdd(&counts[dst[e]], 1);
}

// exclusive prefix of counts -> cursor (counts preserved). One block, 256 threads.
__global__ __launch_bounds__(256) void scan_kernel(
    const int* __restrict__ counts, int* __restrict__ cursor, int n)
{
    __shared__ int part[256];
    int t = threadIdx.x;
    int c = n / 256;
    int base = t * c;
    int s = 0;
    for (int i = 0; i < c; ++i) s += counts[base + i];
    part[t] = s;
    __syncthreads();
    for (int o = 1; o < 256; o <<= 1) {
        int u = (t >= o) ? part[t - o] : 0;
        __syncthreads();
        part[t] += u;
        __syncthreads();
    }
    int run = part[t] - s;  // exclusive base for this chunk
    for (int i = 0; i < c; ++i) {
        cursor[base + i] = run;
        run += counts[base + i];
    }
}

__global__ void scatter_kernel(const int* __restrict__ dst, int* __restrict__ cursor,
                               int* __restrict__ order, int ne) {
    int e = blockIdx.x * 256 + threadIdx.x;
    if (e < ne) {
        int p = atomicAdd(&cursor[dst[e]], 1);
        order[p] = e;
    }
}

// ============ MFMA edge kernel v3: dst-sorted edges, run-aggregated atomics ============
template <int F, int K1S>
__global__ __launch_bounds__(256, 4) void edge_mfma(
    const int* __restrict__ order,
    const float* __restrict__ coords, const float* __restrict__ h,
    const int* __restrict__ src, const int* __restrict__ dst,
    const float* __restrict__ efeat,
    const float* __restrict__ w1, const float* __restrict__ b1,
    const float* __restrict__ g, const float* __restrict__ bt,
    const float* __restrict__ w2, const float* __restrict__ b2,
    const float* __restrict__ cw1, const float* __restrict__ cb1,
    const float* __restrict__ cw2, const float* __restrict__ cb2,
    float* __restrict__ aggr, float* __restrict__ xacc)
{
    constexpr int IN = 143 + F;
    constexpr int KP = K1S * 32 + 8;
    constexpr int XBYTES = 64 * KP * 2;
    static_assert(XBYTES >= 64 * 68 * 4, "f32 alias must fit in xb");
    __shared__ __align__(16) char smem[XBYTES];
    __shared__ __align__(16) unsigned short h1b[64 * 72];
    __shared__ float sums[256], sums2[256];
    __shared__ float stat_m[64], stat_r[64];
    __shared__ float coefp[4][64];
    __shared__ float coef_all[64];
    __shared__ int dsts[64];
    __shared__ float xr_s[64][3], d2s[64];
    unsigned short* xb  = (unsigned short*)smem;
    float*          h1f = (float*)smem;   // alias after GEMM1 (regs) + barrier
    float*          msgf = (float*)smem;  // alias after h1b built (f32 msgs, stride 68)

    const int t  = threadIdx.x;
    const int wv = t >> 6;
    const int L  = t & 63;
    const int lm = L & 15;
    const int qd = L >> 4;
    const int e0 = blockIdx.x * 64;
    const int n  = wv * 16 + lm;

    bfrag8 w1f[K1S], w2f[2], c1f[2];
    #pragma unroll
    for (int kk = 0; kk < K1S; ++kk)
        #pragma unroll
        for (int j = 0; j < 8; ++j) {
            int k = kk * 32 + qd * 8 + j;
            w1f[kk][j] = (k < IN) ? bfbits(w1[k * 64 + n]) : (short)0;
        }
    #pragma unroll
    for (int kk = 0; kk < 2; ++kk)
        #pragma unroll
        for (int j = 0; j < 8; ++j) {
            int k = kk * 32 + qd * 8 + j;
            w2f[kk][j] = bfbits(w2[k * 64 + n]);
            c1f[kk][j] = bfbits(cw1[k * 64 + n]);
        }
    const float b1n = b1[n], b2n = b2[n], cb1n = cb1[n], cw2n = cw2[n];

    if (t < 64) {
        int e = order[e0 + t];
        int s = src[e], d = dst[e];
        dsts[t] = d;
        float x0 = coords[s * 3 + 0] - coords[d * 3 + 0];
        float x1 = coords[s * 3 + 1] - coords[d * 3 + 1];
        float x2 = coords[s * 3 + 2] - coords[d * 3 + 2];
        xr_s[t][0] = x0; xr_s[t][1] = x1; xr_s[t][2] = x2;
        d2s[t] = x0 * x0 + x1 * x1 + x2 * x2;
    }

    for (int p = 0; p < 16; ++p) {
        int e = (t >> 6) + 4 * p;         // local edge, wave-uniform
        int ge = order[e0 + e];
        int s = src[ge], d = dst[ge];
        int j = t & 63;
        xb[e * KP + j]      = bfbits(h[(size_t)s * 64 + j]);
        xb[e * KP + 64 + j] = bfbits(h[(size_t)d * 64 + j]);
    }
    for (int idx = t; idx < 64 * F; idx += 256) {
        int e = idx / F, f = idx - e * F;
        xb[e * KP + 128 + f] = bfbits(efeat[(size_t)order[e0 + e] * F + f]);
    }
    {
        constexpr int PER = K1S * 32 - IN;
        for (int idx = t; idx < 64 * PER; idx += 256) {
            int e = idx / PER, k = idx - e * PER;
            xb[e * KP + IN + k] = 0;
        }
    }
    __syncthreads();
    for (int idx = t; idx < 64 * 15; idx += 256) {
        int e = idx / 15, s5 = idx - e * 15;
        xb[e * KP + 128 + F + s5] = bfbits(__expf(-d2s[e] * c_inv_sigma[s5]));
    }
    __syncthreads();

    // ---- GEMM 1 into registers ----
    f32x4 acc1[4];
    #pragma unroll
    for (int m = 0; m < 4; ++m) {
        f32x4 acc = {0.f, 0.f, 0.f, 0.f};
        #pragma unroll
        for (int kk = 0; kk < K1S; ++kk) {
            bfrag8 a = *(const bfrag8*)&xb[(m * 16 + lm) * KP + kk * 32 + qd * 8];
            acc = __builtin_amdgcn_mfma_f32_16x16x32_bf16(a, w1f[kk], acc, 0, 0, 0);
        }
        acc1[m] = acc;
    }
    __syncthreads();   // xb reads done -> h1f alias live
    #pragma unroll
    for (int m = 0; m < 4; ++m)
        #pragma unroll
        for (int r = 0; r < 4; ++r) {
            int mr = m * 16 + qd * 4 + r;
            float v = acc1[m][r] + b1n;
            v = v > 0.f ? v : 0.01f * v;
            h1f[mr * 68 + n] = v;
        }
    __syncthreads();

    // ---- LayerNorm ----
    {
        int e = t >> 2, seg = (t & 3) * 16;
        float s1 = 0.f, s2 = 0.f;
        #pragma unroll
        for (int j = 0; j < 16; ++j) {
            float v = h1f[e * 68 + seg + j];
            s1 += v; s2 += v * v;
        }
        sums[t] = s1; sums2[t] = s2;
    }
    __syncthreads();
    if (t < 64) {
        float s1 = sums[4 * t] + sums[4 * t + 1] + sums[4 * t + 2] + sums[4 * t + 3];
        float s2 = sums2[4 * t] + sums2[4 * t + 1] + sums2[4 * t + 2] + sums2[4 * t + 3];
        float mean = s1 * (1.f / 64.f);
        float var = s2 * (1.f / 64.f) - mean * mean;
        stat_m[t] = mean;
        stat_r[t] = rsqrtf(fmaxf(var, 0.f) + 1e-5f);
    }
    __syncthreads();
    for (int idx = t; idx < 4096; idx += 256) {
        int e = idx >> 6, j = idx & 63;
        float v = (h1f[e * 68 + j] - stat_m[e]) * stat_r[e] * g[j] + bt[j];
        h1b[e * 72 + j] = bfbits(v);
    }
    __syncthreads();   // h1b ready; h1f dead -> msgf alias OK

    // ---- GEMM 2: msg = H1n @ W2 + b2 -> msgf (f32) ----
    #pragma unroll
    for (int m = 0; m < 4; ++m) {
        f32x4 acc = {0.f, 0.f, 0.f, 0.f};
        #pragma unroll
        for (int kk = 0; kk < 2; ++kk) {
            bfrag8 a = *(const bfrag8*)&h1b[(m * 16 + lm) * 72 + kk * 32 + qd * 8];
            acc = __builtin_amdgcn_mfma_f32_16x16x32_bf16(a, w2f[kk], acc, 0, 0, 0);
        }
        #pragma unroll
        for (int r = 0; r < 4; ++r) {
            int mr = m * 16 + qd * 4 + r;
            msgf[mr * 68 + n] = acc[r] + b2n;
        }
    }
    __syncthreads();

    // ---- run-aggregated aggr atomics (sorted dsts => few runs per block) ----
    {
        int j = t & 63, q = t >> 6;
        float acc = 0.f;
        #pragma unroll
        for (int e = q * 16; e < q * 16 + 16; ++e) {
            acc += msgf[e * 68 + j];
            bool flush = (e - q * 16 == 15) || (dsts[e + 1] != dsts[e]);
            if (flush) {
                atomicAdd(&aggr[(size_t)dsts[e] * 64 + j], acc);
                acc = 0.f;
            }
        }
    }

    // ---- GEMM 3: T = lrelu(msg @ CW1 + cb1); coef = T . cw2 ----
    #pragma unroll
    for (int m = 0; m < 4; ++m) {
        f32x4 acc = {0.f, 0.f, 0.f, 0.f};
        #pragma unroll
        for (int kk = 0; kk < 2; ++kk) {
            int idx = (m * 16 + lm) * 68 + kk * 32 + qd * 8;
            float4 fa = *(const float4*)&msgf[idx];
            float4 fb = *(const float4*)&msgf[idx + 4];
            bfrag8 a;
            a[0] = bfbits(fa.x); a[1] = bfbits(fa.y); a[2] = bfbits(fa.z); a[3] = bfbits(fa.w);
            a[4] = bfbits(fb.x); a[5] = bfbits(fb.y); a[6] = bfbits(fb.z); a[7] = bfbits(fb.w);
            acc = __builtin_amdgcn_mfma_f32_16x16x32_bf16(a, c1f[kk], acc, 0, 0, 0);
        }
        #pragma unroll
        for (int r = 0; r < 4; ++r) {
            float v = acc[r] + cb1n;
            v = v > 0.f ? v : 0.01f * v;
            v *= cw2n;
            v += __shfl_xor(v, 1);
            v += __shfl_xor(v, 2);
            v += __shfl_xor(v, 4);
            v += __shfl_xor(v, 8);
            if (lm == 0) coefp[wv][m * 16 + qd * 4 + r] = v;
        }
    }
    __syncthreads();
    if (t < 64)
        coef_all[t] = coefp[0][t] + coefp[1][t] + coefp[2][t] + coefp[3][t] + cb2[0];
    __syncthreads();

    // ---- run-aggregated xacc atomics (12 walker threads: 4 quarters x 3 axes) ----
    if (t < 12) {
        int q = t / 3, ax = t - q * 3;
        float acc = 0.f;
        for (int e = q * 16; e < q * 16 + 16; ++e) {
            acc += xr_s[e][ax] * coef_all[e];
            bool flush = (e - q * 16 == 15) || (dsts[e + 1] != dsts[e]);
            if (flush) {
                atomicAdd(&xacc[dsts[e] * 3 + ax], acc);
                acc = 0.f;
            }
        }
    }
}

// ---------------- k/v projection (bf16 out) ----------------
__global__ __launch_bounds__(64) void linear64_kernel(
    const float* __restrict__ h, const float* __restrict__ w,
    bf16* __restrict__ out, int do_lrelu)
{
    int node = blockIdx.x;
    int j = threadIdx.x;
    __shared__ float x[64];
    x[j] = h[(size_t)node * 64 + j];
    __syncthreads();
    float acc = 0.f;
    #pragma unroll 8
    for (int i = 0; i < 64; ++i) acc += x[i] * w[i * 64 + j];
    if (do_lrelu) acc = acc > 0.f ? acc : 0.01f * acc;
    out[(size_t)node * 64 + j] = __float2bfloat16(acc);
}

// ---------------- u8 mask build ----------------
__global__ __launch_bounds__(256) void build_masks(
    const float* __restrict__ mask, unsigned char* __restrict__ m8,
    unsigned char* __restrict__ m8T, int R, int C)
{
    __shared__ __align__(16) unsigned char tl[64 * 80];
    int r0 = blockIdx.y * 64, c0 = blockIdx.x * 64;
    int t = threadIdx.x;
    int cs = (t & 15) * 4;
    #pragma unroll
    for (int rr = 0; rr < 4; ++rr) {
        int r = (t >> 4) + rr * 16;
        unsigned b0 = (mask[(size_t)(r0 + r) * C + c0 + cs + 0] != 0.f);
        unsigned b1 = (mask[(size_t)(r0 + r) * C + c0 + cs + 1] != 0.f);
        unsigned b2 = (mask[(size_t)(r0 + r) * C + c0 + cs + 2] != 0.f);
        unsigned b3 = (mask[(size_t)(r0 + r) * C + c0 + cs + 3] != 0.f);
        *(unsigned*)&m8[(size_t)(r0 + r) * C + c0 + cs] = b0 | (b1 << 8) | (b2 << 16) | (b3 << 24);
        tl[(cs + 0) * 80 + r] = (unsigned char)b0;
        tl[(cs + 1) * 80 + r] = (unsigned char)b1;
        tl[(cs + 2) * 80 + r] = (unsigned char)b2;
        tl[(cs + 3) * 80 + r] = (unsigned char)b3;
    }
    __syncthreads();
    {
        int c = t >> 2, rs = (t & 3) * 16;
        *(uint4*)&m8T[(size_t)(c0 + c) * R + r0 + rs] = *(const uint4*)&tl[c * 80 + rs];
    }
}

// ============ MFMA flash attention, both directions in one launch ============
template <int MMODE>
__global__ __launch_bounds__(256) void attn_mfma(
    int nb1,
    const float* __restrict__ h1, const float* __restrict__ qw1,
    const bf16* __restrict__ k1, const bf16* __restrict__ v1,
    const unsigned char* __restrict__ m81, const float* __restrict__ mf1, long mrs1, long mcs1,
    float* __restrict__ pO1, float* __restrict__ pM1, float* __restrict__ pL1,
    int nrows1, int ncols1, int nsplit1,
    const float* __restrict__ h2, const float* __restrict__ qw2,
    const bf16* __restrict__ k2, const bf16* __restrict__ v2,
    const unsigned char* __restrict__ m82, const float* __restrict__ mf2, long mrs2, long mcs2,
    float* __restrict__ pO2, float* __restrict__ pM2, float* __restrict__ pL2,
    int nrows2, int ncols2, int nsplit2)
{
    const float *h, *qw, *mf;
    const bf16 *kkp, *vvp;
    const unsigned char* m8;
    long mrs, mcs;
    float *pO, *pM, *pL;
    int n_rows, n_cols, nsplit, bid;
    if ((int)blockIdx.x < nb1) {
        h = h1; qw = qw1; kkp = k1; vvp = v1; m8 = m81; mf = mf1; mrs = mrs1; mcs = mcs1;
        pO = pO1; pM = pM1; pL = pL1; n_rows = nrows1; n_cols = ncols1; nsplit = nsplit1;
        bid = blockIdx.x;
    } else {
        h = h2; qw = qw2; kkp = k2; vvp = v2; m8 = m82; mf = mf2; mrs = mrs2; mcs = mcs2;
        pO = pO2; pM = pM2; pL = pL2; n_rows = nrows2; n_cols = ncols2; nsplit = nsplit2;
        bid = blockIdx.x - nb1;
    }

    const int t  = threadIdx.x;
    const int wv = t >> 6;
    const int lm = t & 15;
    const int qd = (t & 63) >> 4;
    const int rb = bid / nsplit;
    const int sp = bid - rb * nsplit;
    const int r0 = rb * 64;
    const int cols_per = n_cols / nsplit;
    const int c_begin = sp * cols_per;

    __shared__ __align__(16) unsigned short qb[64 * 72];
    __shared__ __align__(16) unsigned short kvb[64 * 72];
    __shared__ __align__(16) unsigned short pb[64 * 72];
    __shared__ __align__(16) unsigned char mt[4096];

    {
        int r = t >> 3, seg = (t & 7) * 8;
        #pragma unroll
        for (int u = 0; u < 2; ++u) {
            int rr = r + 32 * u;
            const float* hp = h + (size_t)(r0 + rr) * 64 + seg;
            unsigned short tmp[8];
            #pragma unroll
            for (int j = 0; j < 8; ++j) tmp[j] = bfbits(hp[j]);
            *(uint4*)&qb[rr * 72 + seg] = *(uint4*)tmp;
            const float* qp = qw + (size_t)rr * 64 + seg;
            #pragma unroll
            for (int j = 0; j < 8; ++j) kvb[(seg + j) * 72 + rr] = bfbits(qp[j]);
        }
    }
    __syncthreads();
    {
        bfrag8 a0 = *(const bfrag8*)&qb[(wv * 16 + lm) * 72 + qd * 8];
        bfrag8 a1 = *(const bfrag8*)&qb[(wv * 16 + lm) * 72 + 32 + qd * 8];
        #pragma unroll
        for (int ns = 0; ns < 4; ++ns) {
            f32x4 acc = {0.f, 0.f, 0.f, 0.f};
            bfrag8 b0 = *(const bfrag8*)&kvb[(ns * 16 + lm) * 72 + qd * 8];
            bfrag8 b1 = *(const bfrag8*)&kvb[(ns * 16 + lm) * 72 + 32 + qd * 8];
            acc = __builtin_amdgcn_mfma_f32_16x16x32_bf16(a0, b0, acc, 0, 0, 0);
            acc = __builtin_amdgcn_mfma_f32_16x16x32_bf16(a1, b1, acc, 0, 0, 0);
            #pragma unroll
            for (int r = 0; r < 4; ++r) {
                float v = acc[r];
                v = v > 0.f ? v : 0.01f * v;
                pb[(wv * 16 + qd * 4 + r) * 72 + ns * 16 + lm] = bfbits(v);
            }
        }
    }
    __syncthreads();
    for (int idx = t; idx < 64 * 9; idx += 256) {
        int r = idx / 9, seg = (idx - r * 9) * 8;
        if (seg < 64) *(uint4*)&qb[r * 72 + seg] = *(const uint4*)&pb[r * 72 + seg];
    }
    __syncthreads();

    float rm[4], rl[4];
    #pragma unroll
    for (int r = 0; r < 4; ++r) { rm[r] = -1e30f; rl[r] = 0.f; }
    f32x4 o[4];
    #pragma unroll
    for (int ds = 0; ds < 4; ++ds) o[ds] = (f32x4){0.f, 0.f, 0.f, 0.f};

    for (int c0 = c_begin; c0 < c_begin + cols_per; c0 += 64) {
        {
            int c = t >> 3, seg = (t & 7) * 8;
            #pragma unroll
            for (int u = 0; u < 2; ++u) {
                int cc = c + 32 * u;
                *(uint4*)&kvb[cc * 72 + seg] =
                    *(const uint4*)(kkp + (size_t)(c0 + cc) * 64 + seg);
            }
        }
        if (MMODE == 0) {
            int r = t >> 2, seg = (t & 3) * 16;
            *(uint4*)&mt[r * 64 + seg] =
                *(const uint4*)&m8[(size_t)(r0 + r) * n_cols + c0 + seg];
        } else {
            #pragma unroll
            for (int u = 0; u < 16; ++u) {
                int i = t + 256 * u;
                int r = i >> 6, c = i & 63;
                mt[r * 64 + c] = (unsigned char)(
                    mf[(size_t)(r0 + r) * mrs + (size_t)(c0 + c) * mcs] != 0.f);
            }
        }
        __syncthreads();

        f32x4 s[4];
        {
            bfrag8 a0 = *(const bfrag8*)&qb[(wv * 16 + lm) * 72 + qd * 8];
            bfrag8 a1 = *(const bfrag8*)&qb[(wv * 16 + lm) * 72 + 32 + qd * 8];
            #pragma unroll
            for (int ns = 0; ns < 4; ++ns) {
                f32x4 acc = {0.f, 0.f, 0.f, 0.f};
                bfrag8 b0 = *(const bfrag8*)&kvb[(ns * 16 + lm) * 72 + qd * 8];
                bfrag8 b1 = *(const bfrag8*)&kvb[(ns * 16 + lm) * 72 + 32 + qd * 8];
                acc = __builtin_amdgcn_mfma_f32_16x16x32_bf16(a0, b0, acc, 0, 0, 0);
                acc = __builtin_amdgcn_mfma_f32_16x16x32_bf16(a1, b1, acc, 0, 0, 0);
                s[ns] = acc;
            }
        }
        float alpha[4];
        #pragma unroll
        for (int r = 0; r < 4; ++r) {
            int rloc = wv * 16 + qd * 4 + r;
            float v0 = mt[rloc * 64 +  0 + lm] ? s[0][r] : -1000.f;
            float v1 = mt[rloc * 64 + 16 + lm] ? s[1][r] : -1000.f;
            float v2 = mt[rloc * 64 + 32 + lm] ? s[2][r] : -1000.f;
            float v3 = mt[rloc * 64 + 48 + lm] ? s[3][r] : -1000.f;
            float mx = quad_max(fmaxf(fmaxf(v0, v1), fmaxf(v2, v3)));
            float mn = fmaxf(rm[r], mx);
            float al = __expf(rm[r] - mn);
            rm[r] = mn; alpha[r] = al;
            float p0 = __expf(v0 - mn), p1 = __expf(v1 - mn);
            float p2 = __expf(v2 - mn), p3 = __expf(v3 - mn);
            pb[rloc * 72 +  0 + lm] = bfbits(p0);
            pb[rloc * 72 + 16 + lm] = bfbits(p1);
            pb[rloc * 72 + 32 + lm] = bfbits(p2);
            pb[rloc * 72 + 48 + lm] = bfbits(p3);
            float ls = quad_sum(p0 + p1 + p2 + p3);
            rl[r] = rl[r] * al + ls;
        }
        #pragma unroll
        for (int ds = 0; ds < 4; ++ds)
            #pragma unroll
            for (int r = 0; r < 4; ++r) o[ds][r] *= alpha[r];
        __syncthreads();

        {
            int c = t >> 3, seg = (t & 7) * 8;
            #pragma unroll
            for (int u = 0; u < 2; ++u) {
                int cc = c + 32 * u;
                uint4 raw = *(const uint4*)(vvp + (size_t)(c0 + cc) * 64 + seg);
                unsigned short* pr = (unsigned short*)&raw;
                #pragma unroll
                for (int j = 0; j < 8; ++j) kvb[(seg + j) * 72 + cc] = pr[j];
            }
        }
        __syncthreads();

        {
            bfrag8 a0 = *(const bfrag8*)&pb[(wv * 16 + lm) * 72 + qd * 8];
            bfrag8 a1 = *(const bfrag8*)&pb[(wv * 16 + lm) * 72 + 32 + qd * 8];
            #pragma unroll
            for (int ds = 0; ds < 4; ++ds) {
                bfrag8 b0 = *(const bfrag8*)&kvb[(ds * 16 + lm) * 72 + qd * 8];
                bfrag8 b1 = *(const bfrag8*)&kvb[(ds * 16 + lm) * 72 + 32 + qd * 8];
                o[ds] = __builtin_amdgcn_mfma_f32_16x16x32_bf16(a0, b0, o[ds], 0, 0, 0);
                o[ds] = __builtin_amdgcn_mfma_f32_16x16x32_bf16(a1, b1, o[ds], 0, 0, 0);
            }
        }
        __syncthreads();
    }

    #pragma unroll
    for (int ds = 0; ds < 4; ++ds)
        #pragma unroll
        for (int r = 0; r < 4; ++r) {
            int row = r0 + wv * 16 + qd * 4 + r;
            pO[((size_t)sp * n_rows + row) * 64 + ds * 16 + lm] = o[ds][r];
        }
    if (lm == 0) {
        #pragma unroll
        for (int r = 0; r < 4; ++r) {
            int row = r0 + wv * 16 + qd * 4 + r;
            pM[(size_t)sp * n_rows + row] = rm[r];
            pL[(size_t)sp * n_rows + row] = rl[r];
        }
    }
}

// ---------------- merge split partials ----------------
__global__ __launch_bounds__(64) void attn_merge(
    const float* __restrict__ pO, const float* __restrict__ pM, const float* __restrict__ pL,
    float* __restrict__ out, int n_rows, int nsplit)
{
    int r = blockIdx.x;
    int d = threadIdx.x;
    float mstar = -1e30f;
    for (int s = 0; s < nsplit; ++s) mstar = fmaxf(mstar, pM[(size_t)s * n_rows + r]);
    float L = 0.f, O = 0.f;
    for (int s = 0; s < nsplit; ++s) {
        float w = __expf(pM[(size_t)s * n_rows + r] - mstar);
        L += pL[(size_t)s * n_rows + r] * w;
        O += pO[((size_t)s * n_rows + r) * 64 + d] * w;
    }
    out[(size_t)r * 64 + d] = O / L;
}

// ---------------- per-row attention (tier-2 fallback) ----------------
__global__ __launch_bounds__(256) void attn_row_kernel(
    const float* __restrict__ h, const float* __restrict__ qw,
    const bf16* __restrict__ k, const bf16* __restrict__ v,
    const float* __restrict__ mask, long mrs, long mcs,
    float* __restrict__ out, int n_cols)
{
    int row = blockIdx.x;
    int tid = threadIdx.x;
    extern __shared__ float sc[];
    __shared__ float hrow[64];
    __shared__ float qrow[64];
    __shared__ float red[4];
    __shared__ float opart[4][64];

    if (tid < 64) hrow[tid] = h[(size_t)row * 64 + tid];
    __syncthreads();
    if (tid < 64) {
        float a = 0.f;
        #pragma unroll 8
        for (int i = 0; i < 64; ++i) a += hrow[i] * qw[i * 64 + tid];
        qrow[tid] = a > 0.f ? a : 0.01f * a;
    }
    __syncthreads();

    float lmax = -1e30f;
    for (int c = tid; c < n_cols; c += 256) {
        const bf16* kr = k + (size_t)c * 64;
        float s = 0.f;
        #pragma unroll 8
        for (int i = 0; i < 64; ++i) s += qrow[i] * ldkv(kr, i);
        float m = mask[(size_t)row * mrs + (size_t)c * mcs];
        s = m * s - 1000.f * (1.f - m);
        sc[c] = s;
        lmax = fmaxf(lmax, s);
    }
    #pragma unroll
    for (int o = 32; o > 0; o >>= 1) lmax = fmaxf(lmax, __shfl_xor(lmax, o, 64));
    int wid = tid >> 6;
    if ((tid & 63) == 0) red[wid] = lmax;
    __syncthreads();
    float bmax = fmaxf(fmaxf(red[0], red[1]), fmaxf(red[2], red[3]));
    __syncthreads();

    float lsum = 0.f;
    for (int c = tid; c < n_cols; c += 256) {
        float e = __expf(sc[c] - bmax);
        sc[c] = e;
        lsum += e;
    }
    lsum = wave_sum(lsum);
    if ((tid & 63) == 0) red[wid] = lsum;
    __syncthreads();
    float inv = 1.f / (red[0] + red[1] + red[2] + red[3]);

    int dd = tid & 63;
    float o = 0.f;
    for (int c = wid; c < n_cols; c += 4) o += sc[c] * ldkv(v, (size_t)c * 64 + dd);
    opart[wid][dd] = o;
    __syncthreads();
    if (wid == 0)
        out[(size_t)row * 64 + dd] =
            (opart[0][dd] + opart[1][dd] + opart[2][dd] + opart[3][dd]) * inv;
}

// ---------------- node feature update (cnt from CSR histogram, int) ----------------
__global__ __launch_bounds__(64) void node_kernel(
    const float* __restrict__ h, const float* __restrict__ aggr,
    const int* __restrict__ cnt, const float* att,  // aliases h_out
    const float* __restrict__ orig_h,
    const float* __restrict__ w1, const float* __restrict__ b1,
    const float* __restrict__ g, const float* __restrict__ bt,
    const float* __restrict__ w2, const float* __restrict__ b2,
    float* h_out)
{
    int node = blockIdx.x;
    int j = threadIdx.x;
    __shared__ float xin[256];
    __shared__ float hbuf[64];
    float invc = 1.f / fmaxf((float)cnt[node], 1.f);
    float hv = h[(size_t)node * 64 + j];
    xin[j]       = hv;
    xin[64 + j]  = aggr[(size_t)node * 64 + j] * invc;
    xin[128 + j] = att[(size_t)node * 64 + j];
    xin[192 + j] = orig_h[(size_t)node * 64 + j];
    __syncthreads();
    float acc = b1[j];
    #pragma unroll 4
    for (int i = 0; i < 256; ++i) acc += xin[i] * w1[i * 64 + j];
    acc = acc > 0.f ? acc : 0.01f * acc;
    float mean = wave_sum(acc) * (1.f / 64.f);
    float cv = acc - mean;
    float var = wave_sum(cv * cv) * (1.f / 64.f);
    float y = cv * rsqrtf(var + 1e-5f) * g[j] + bt[j];
    hbuf[j] = y;
    __syncthreads();
    float o = b2[j];
    #pragma unroll 8
    for (int i = 0; i < 64; ++i) o += hbuf[i] * w2[i * 64 + j];
    h_out[(size_t)node * 64 + j] = 0.5f * o + 0.5f * hv;
}

// ---------------- coordinate output ----------------
__global__ void coord_kernel(
    const float* __restrict__ orig, const float* __restrict__ coords,
    const float* __restrict__ xacc, const int* __restrict__ cnt,
    float* __restrict__ out, int n3)
{
    int i = blockIdx.x * blockDim.x + threadIdx.x;
    if (i >= n3) return;
    int node = i / 3;
    float invc = 1.f / fmaxf((float)cnt[node], 1.f);
    out[i] = 0.25f * orig[i] + 0.75f * coords[i] + xacc[i] * invc;
}

extern "C" void kernel_launch(void* const* d_in, const int* in_sizes, int n_in,
                              void* d_out, int out_size, void* d_ws, size_t ws_size,
                              hipStream_t stream)
{
    const float* coords_lig      = (const float*)d_in[0];
    const float* h_lig           = (const float*)d_in[1];
    const float* orig_h_lig      = (const float*)d_in[2];
    const float* orig_coords_lig = (const float*)d_in[3];
    const float* coords_rec      = (const float*)d_in[4];
    const float* h_rec           = (const float*)d_in[5];
    const float* orig_h_rec      = (const float*)d_in[6];
    const float* orig_coords_rec = (const float*)d_in[7];
    const int* lig_src   = (const int*)d_in[8];
    const int* lig_dst   = (const int*)d_in[9];
    const float* lig_efeat = (const float*)d_in[10];
    const int* rec_src   = (const int*)d_in[11];
    const int* rec_dst   = (const int*)d_in[12];
    const float* rec_efeat = (const float*)d_in[13];
    const float* mask      = (const float*)d_in[14];
    const float *lig_em_w1 = (const float*)d_in[15], *lig_em_b1 = (const float*)d_in[16];
    const float *lig_em_g  = (const float*)d_in[17], *lig_em_bt = (const float*)d_in[18];
    const float *lig_em_w2 = (const float*)d_in[19], *lig_em_b2 = (const float*)d_in[20];
    const float *rec_em_w1 = (const float*)d_in[21], *rec_em_b1 = (const float*)d_in[22];
    const float *rec_em_g  = (const float*)d_in[23], *rec_em_bt = (const float*)d_in[24];
    const float *rec_em_w2 = (const float*)d_in[25], *rec_em_b2 = (const float*)d_in[26];
    const float *lig_cm_w1 = (const float*)d_in[27], *lig_cm_b1 = (const float*)d_in[28];
    const float *lig_cm_w2 = (const float*)d_in[29], *lig_cm_b2 = (const float*)d_in[30];
    const float *rec_cm_w1 = (const float*)d_in[31], *rec_cm_b1 = (const float*)d_in[32];
    const float *rec_cm_w2 = (const float*)d_in[33], *rec_cm_b2 = (const float*)d_in[34];
    const float *q_lig_w = (const float*)d_in[35], *k_lig_w = (const float*)d_in[36];
    const float *v_lig_w = (const float*)d_in[37], *q_rec_w = (const float*)d_in[38];
    const float *k_rec_w = (const float*)d_in[39], *v_rec_w = (const float*)d_in[40];
    const float *lig_nm_w1 = (const float*)d_in[41], *lig_nm_b1 = (const float*)d_in[42];
    const float *lig_nm_g  = (const float*)d_in[43], *lig_nm_bt = (const float*)d_in[44];
    const float *lig_nm_w2 = (const float*)d_in[45], *lig_nm_b2 = (const float*)d_in[46];
    const float *rec_nm_w1 = (const float*)d_in[47], *rec_nm_b1 = (const float*)d_in[48];
    const float *rec_nm_g  = (const float*)d_in[49], *rec_nm_bt = (const float*)d_in[50];
    const float *rec_nm_w2 = (const float*)d_in[51], *rec_nm_b2 = (const float*)d_in[52];

    char* wsb = (char*)d_ws;
    float* aggr_l = (float*)(wsb + 16);
    float* aggr_r = aggr_l + (size_t)N_LIG * 64;
    float* xacc_l = aggr_r + (size_t)N_REC * 64;
    float* xacc_r = xacc_l + (size_t)N_LIG * 3;
    int* counts_l = (int*)(xacc_r + (size_t)N_REC * 3);
    int* counts_r = counts_l + N_LIG;
    const size_t zero_floats =
        (size_t)N_LIG * 64 + (size_t)N_REC * 64 + N_LIG * 3 + N_REC * 3 + N_LIG + N_REC;
    int* cursor_l = counts_r + N_REC;
    int* cursor_r = cursor_l + N_LIG;
    int* order_l  = cursor_r + N_REC;
    int* order_r  = order_l + E_LIG;
    char* kv_base = (char*)(order_r + E_REC);
    const size_t core_b = (size_t)(kv_base - wsb);
    const size_t kv_b = (size_t)(N_LIG + N_REC) * 64 * 2 * 2;   // bf16 k+v both graphs
    const size_t part_b = ((size_t)4 * N_LIG * 64 + (size_t)2 * N_REC * 64) * 4
                        + ((size_t)4 * N_LIG + (size_t)2 * N_REC) * 2 * 4;
    const size_t m8_b = (size_t)N_LIG * N_REC;

    int tier;
    if (ws_size >= core_b + kv_b + part_b + 2 * m8_b) tier = 0;
    else if (ws_size >= core_b + kv_b + part_b) tier = 1;
    else tier = 2;

    bf16* kb_l = (bf16*)kv_base;
    bf16* vb_l = kb_l + (size_t)N_LIG * 64;
    bf16* kb_r = vb_l + (size_t)N_LIG * 64;
    bf16* vb_r = kb_r + (size_t)N_REC * 64;
    float* pO1 = (float*)(kv_base + kv_b);
    float* pO2 = pO1 + (size_t)4 * N_LIG * 64;
    float* pM1 = pO2 + (size_t)2 * N_REC * 64;
    float* pL1 = pM1 + (size_t)4 * N_LIG;
    float* pM2 = pL1 + (size_t)4 * N_LIG;
    float* pL2 = pM2 + (size_t)2 * N_REC;
    unsigned char* m8  = (unsigned char*)(kv_base + kv_b + part_b);
    unsigned char* m8T = m8 + m8_b;

    float* out = (float*)d_out;
    float* x_lig_o = out;
    float* h_lig_o = out + 12288;
    float* x_rec_o = out + 274432;
    float* h_rec_o = out + 299008;

    zero_kernel<<<((int)zero_floats + 255) / 256, 256, 0, stream>>>(aggr_l, (int)zero_floats);

    // counting sort by dst (both graphs)
    hist_kernel<<<E_LIG / 256, 256, 0, stream>>>(lig_dst, counts_l, E_LIG);
    hist_kernel<<<E_REC / 256, 256, 0, stream>>>(rec_dst, counts_r, E_REC);
    scan_kernel<<<1, 256, 0, stream>>>(counts_l, cursor_l, N_LIG);
    scan_kernel<<<1, 256, 0, stream>>>(counts_r, cursor_r, N_REC);
    scatter_kernel<<<E_LIG / 256, 256, 0, stream>>>(lig_dst, cursor_l, order_l, E_LIG);
    scatter_kernel<<<E_REC / 256, 256, 0, stream>>>(rec_dst, cursor_r, order_r, E_REC);

    // k/v projections (bf16)
    linear64_kernel<<<N_LIG, 64, 0, stream>>>(h_lig, k_lig_w, kb_l, 1);
    linear64_kernel<<<N_LIG, 64, 0, stream>>>(h_lig, v_lig_w, vb_l, 0);
    linear64_kernel<<<N_REC, 64, 0, stream>>>(h_rec, k_rec_w, kb_r, 1);
    linear64_kernel<<<N_REC, 64, 0, stream>>>(h_rec, v_rec_w, vb_r, 0);

    // MFMA edge kernels (dst-sorted, run-aggregated)
    edge_mfma<F_LIGc, 5><<<E_LIG / 64, 256, 0, stream>>>(
        order_l, coords_lig, h_lig, lig_src, lig_dst, lig_efeat,
        lig_em_w1, lig_em_b1, lig_em_g, lig_em_bt, lig_em_w2, lig_em_b2,
        lig_cm_w1, lig_cm_b1, lig_cm_w2, lig_cm_b2,
        aggr_l, xacc_l);
    edge_mfma<F_RECc, 6><<<E_REC / 64, 256, 0, stream>>>(
        order_r, coords_rec, h_rec, rec_src, rec_dst, rec_efeat,
        rec_em_w1, rec_em_b1, rec_em_g, rec_em_bt, rec_em_w2, rec_em_b2,
        rec_cm_w1, rec_cm_b1, rec_cm_w2, rec_cm_b2,
        aggr_r, xacc_r);

    // attention (both directions in one launch)
    const int nb1 = (N_LIG / 64) * 4;
    const int nb2 = (N_REC / 64) * 2;
    if (tier <= 1) {
        if (tier == 0) {
            dim3 bg(N_REC / 64, N_LIG / 64);
            build_masks<<<bg, 256, 0, stream>>>(mask, m8, m8T, N_LIG, N_REC);
            attn_mfma<0><<<nb1 + nb2, 256, 0, stream>>>(
                nb1,
                h_lig, q_lig_w, kb_r, vb_r, m8, mask, 0L, 0L,
                pO1, pM1, pL1, N_LIG, N_REC, 4,
                h_rec, q_rec_w, kb_l, vb_l, m8T, mask, 0L, 0L,
                pO2, pM2, pL2, N_REC, N_LIG, 2);
        } else {
            attn_mfma<1><<<nb1 + nb2, 256, 0, stream>>>(
                nb1,
                h_lig, q_lig_w, kb_r, vb_r, (const unsigned char*)0, mask, (long)N_REC, 1L,
                pO1, pM1, pL1, N_LIG, N_REC, 4,
                h_rec, q_rec_w, kb_l, vb_l, (const unsigned char*)0, mask, 1L, (long)N_REC,
                pO2, pM2, pL2, N_REC, N_LIG, 2);
        }
        attn_merge<<<N_LIG, 64, 0, stream>>>(pO1, pM1, pL1, h_lig_o, N_LIG, 4);
        attn_merge<<<N_REC, 64, 0, stream>>>(pO2, pM2, pL2, h_rec_o, N_REC, 2);
    } else {
        attn_row_kernel<<<N_LIG, 256, N_REC * sizeof(float), stream>>>(
            h_lig, q_lig_w, kb_r, vb_r, mask, (long)N_REC, 1L, h_lig_o, N_REC);
        attn_row_kernel<<<N_REC, 256, N_LIG * sizeof(float), stream>>>(
            h_rec, q_rec_w, kb_l, vb_l, mask, 1L, (long)N_REC, h_rec_o, N_LIG);
    }

    // node updates
    node_kernel<<<N_LIG, 64, 0, stream>>>(
        h_lig, aggr_l, counts_l, h_lig_o, orig_h_lig,
        lig_nm_w1, lig_nm_b1, lig_nm_g, lig_nm_bt, lig_nm_w2, lig_nm_b2, h_lig_o);
    node_kernel<<<N_REC, 64, 0, stream>>>(
        h_rec, aggr_r, counts_r, h_rec_o, orig_h_rec,
        rec_nm_w1, rec_nm_b1, rec_nm_g, rec_nm_bt, rec_nm_w2, rec_nm_b2, h_rec_o);

    // coordinate outputs
    coord_kernel<<<(N_LIG * 3 + 255) / 256, 256, 0, stream>>>(
        orig_coords_lig, coords_lig, xacc_l, counts_l, x_lig_o, N_LIG * 3);
    coord_kernel<<<(N_REC * 3 + 255) / 256, 256, 0, stream>>>(
        orig_coords_rec, coords_rec, xacc_r, counts_r, x_rec_o, N_REC * 3);
}

// Round 11
// 750.663 us; speedup vs baseline: 1.0912x; 1.0706x over previous
//
#include <hip/hip_runtime.h>
#include <hip/hip_bf16.h>

typedef __hip_bfloat16 bf16;
typedef __attribute__((ext_vector_type(8))) short bfrag8;
typedef __attribute__((ext_vector_type(4))) float f32x4;

#define N_LIG 4096
#define N_REC 8192
#define E_LIG 65536
#define E_REC 262144
#define F_LIGc 15
#define F_RECc 27

__device__ __forceinline__ float ldkv(const float* p, size_t i) { return p[i]; }
__device__ __forceinline__ float ldkv(const bf16* p, size_t i) { return __bfloat162float(p[i]); }
__device__ __forceinline__ short bfbits(float x) {
    bf16 b = __float2bfloat16(x);
    return *(short*)&b;
}
__device__ __forceinline__ unsigned short stg(const float* p, size_t i) {
    return (unsigned short)bfbits(p[i]);
}
__device__ __forceinline__ unsigned short stg(const bf16* p, size_t i) {
    return *(const unsigned short*)(p + i);
}

__constant__ float c_inv_sigma[15] = {
    1.0f, 0.6666666667f, 0.4444444444f, 0.2962962963f, 0.1975308642f,
    0.1316872428f, 0.08779149520f, 0.05852766346f, 0.03901844231f,
    0.02601229487f, 0.01734152992f, 0.01156101994f, 0.007707346628f,
    0.005138231085f, 0.003425487390f};

__device__ __forceinline__ float wave_sum(float v) {
    #pragma unroll
    for (int o = 32; o > 0; o >>= 1) v += __shfl_xor(v, o, 64);
    return v;
}
__device__ __forceinline__ float quad_max(float v) {
    v = fmaxf(v, __shfl_xor(v, 1)); v = fmaxf(v, __shfl_xor(v, 2));
    v = fmaxf(v, __shfl_xor(v, 4)); v = fmaxf(v, __shfl_xor(v, 8));
    return v;
}
__device__ __forceinline__ float quad_sum(float v) {
    v += __shfl_xor(v, 1); v += __shfl_xor(v, 2);
    v += __shfl_xor(v, 4); v += __shfl_xor(v, 8);
    return v;
}

__global__ void zero_kernel(float* __restrict__ p, int n) {
    int i = blockIdx.x * blockDim.x + threadIdx.x;
    if (i < n) p[i] = 0.f;
}

__global__ void cvt_kernel(const float* __restrict__ in, bf16* __restrict__ out, int n) {
    int i = blockIdx.x * blockDim.x + threadIdx.x;
    if (i < n) out[i] = __float2bfloat16(in[i]);
}

// ---------------- counting sort ----------------
__global__ void hist_kernel(const int* __restrict__ dst, int* __restrict__ counts, int ne) {
    int e = blockIdx.x * 256 + threadIdx.x;
    if (e < ne) atomicAdd(&counts[dst[e]], 1);
}

__global__ __launch_bounds__(256) void scan_kernel(
    const int* __restrict__ counts, int* __restrict__ cursor, int n)
{
    __shared__ int part[256];
    int t = threadIdx.x;
    int c = n / 256;
    int base = t * c;
    int s = 0;
    for (int i = 0; i < c; ++i) s += counts[base + i];
    part[t] = s;
    __syncthreads();
    for (int o = 1; o < 256; o <<= 1) {
        int u = (t >= o) ? part[t - o] : 0;
        __syncthreads();
        part[t] += u;
        __syncthreads();
    }
    int run = part[t] - s;
    for (int i = 0; i < c; ++i) {
        cursor[base + i] = run;
        run += counts[base + i];
    }
}

__global__ void scatter_kernel(const int* __restrict__ dst, int* __restrict__ cursor,
                               int* __restrict__ order, int ne) {
    int e = blockIdx.x * 256 + threadIdx.x;
    if (e < ne) {
        int p = atomicAdd(&cursor[dst[e]], 1);
        order[p] = e;
    }
}

// ============ MFMA edge kernel v4: bf16 inputs (opt), reg-GEMM2 + dual msg write ============
template <int F, int K1S, typename HT>
__global__ __launch_bounds__(256, 4) void edge_mfma(
    const int* __restrict__ order,
    const float* __restrict__ coords, const HT* __restrict__ h,
    const int* __restrict__ src, const int* __restrict__ dst,
    const HT* __restrict__ efeat,
    const float* __restrict__ w1, const float* __restrict__ b1,
    const float* __restrict__ g, const float* __restrict__ bt,
    const float* __restrict__ w2, const float* __restrict__ b2,
    const float* __restrict__ cw1, const float* __restrict__ cb1,
    const float* __restrict__ cw2, const float* __restrict__ cb2,
    float* __restrict__ aggr, float* __restrict__ xacc)
{
    constexpr int IN = 143 + F;
    constexpr int KP = K1S * 32 + 8;
    constexpr int XBYTES = 64 * KP * 2;
    static_assert(XBYTES >= 64 * 68 * 4, "f32 alias must fit in xb");
    __shared__ __align__(16) char smem[XBYTES];
    __shared__ __align__(16) unsigned short h1b[64 * 72];
    __shared__ float sums[256], sums2[256];
    __shared__ float stat_m[64], stat_r[64];
    __shared__ float coefp[4][64];
    __shared__ float coef_all[64];
    __shared__ int dsts[64];
    __shared__ float xr_s[64][3], d2s[64];
    unsigned short* xb   = (unsigned short*)smem;
    float*          h1f  = (float*)smem;     // alias after GEMM1 regs + barrier
    float*          msgf = (float*)smem;     // alias after h1b built (f32, stride 68)
    unsigned short* msgb = h1b;              // alias after GEMM2 reads done (bf16, stride 72)

    const int t  = threadIdx.x;
    const int wv = t >> 6;
    const int L  = t & 63;
    const int lm = L & 15;
    const int qd = L >> 4;
    const int e0 = blockIdx.x * 64;
    const int n  = wv * 16 + lm;

    bfrag8 w1f[K1S], w2f[2], c1f[2];
    #pragma unroll
    for (int kk = 0; kk < K1S; ++kk)
        #pragma unroll
        for (int j = 0; j < 8; ++j) {
            int k = kk * 32 + qd * 8 + j;
            w1f[kk][j] = (k < IN) ? bfbits(w1[k * 64 + n]) : (short)0;
        }
    #pragma unroll
    for (int kk = 0; kk < 2; ++kk)
        #pragma unroll
        for (int j = 0; j < 8; ++j) {
            int k = kk * 32 + qd * 8 + j;
            w2f[kk][j] = bfbits(w2[k * 64 + n]);
            c1f[kk][j] = bfbits(cw1[k * 64 + n]);
        }
    const float b1n = b1[n], b2n = b2[n], cb1n = cb1[n], cw2n = cw2[n];

    if (t < 64) {
        int e = order[e0 + t];
        int s = src[e], d = dst[e];
        dsts[t] = d;
        float x0 = coords[s * 3 + 0] - coords[d * 3 + 0];
        float x1 = coords[s * 3 + 1] - coords[d * 3 + 1];
        float x2 = coords[s * 3 + 2] - coords[d * 3 + 2];
        xr_s[t][0] = x0; xr_s[t][1] = x1; xr_s[t][2] = x2;
        d2s[t] = x0 * x0 + x1 * x1 + x2 * x2;
    }

    for (int p = 0; p < 16; ++p) {
        int e = (t >> 6) + 4 * p;
        int ge = order[e0 + e];
        int s = src[ge], d = dst[ge];
        int j = t & 63;
        xb[e * KP + j]      = stg(h, (size_t)s * 64 + j);
        xb[e * KP + 64 + j] = stg(h, (size_t)d * 64 + j);
    }
    for (int idx = t; idx < 64 * F; idx += 256) {
        int e = idx / F, f = idx - e * F;
        xb[e * KP + 128 + f] = stg(efeat, (size_t)order[e0 + e] * F + f);
    }
    {
        constexpr int PER = K1S * 32 - IN;
        for (int idx = t; idx < 64 * PER; idx += 256) {
            int e = idx / PER, k = idx - e * PER;
            xb[e * KP + IN + k] = 0;
        }
    }
    __syncthreads();
    for (int idx = t; idx < 64 * 15; idx += 256) {
        int e = idx / 15, s5 = idx - e * 15;
        xb[e * KP + 128 + F + s5] = bfbits(__expf(-d2s[e] * c_inv_sigma[s5]));
    }
    __syncthreads();

    // ---- GEMM 1 into registers ----
    f32x4 acc1[4];
    #pragma unroll
    for (int m = 0; m < 4; ++m) {
        f32x4 acc = {0.f, 0.f, 0.f, 0.f};
        #pragma unroll
        for (int kk = 0; kk < K1S; ++kk) {
            bfrag8 a = *(const bfrag8*)&xb[(m * 16 + lm) * KP + kk * 32 + qd * 8];
            acc = __builtin_amdgcn_mfma_f32_16x16x32_bf16(a, w1f[kk], acc, 0, 0, 0);
        }
        acc1[m] = acc;
    }
    __syncthreads();   // xb reads done -> h1f alias live
    #pragma unroll
    for (int m = 0; m < 4; ++m)
        #pragma unroll
        for (int r = 0; r < 4; ++r) {
            int mr = m * 16 + qd * 4 + r;
            float v = acc1[m][r] + b1n;
            v = v > 0.f ? v : 0.01f * v;
            h1f[mr * 68 + n] = v;
        }
    __syncthreads();

    // ---- LayerNorm ----
    {
        int e = t >> 2, seg = (t & 3) * 16;
        float s1 = 0.f, s2 = 0.f;
        #pragma unroll
        for (int j = 0; j < 16; ++j) {
            float v = h1f[e * 68 + seg + j];
            s1 += v; s2 += v * v;
        }
        sums[t] = s1; sums2[t] = s2;
    }
    __syncthreads();
    if (t < 64) {
        float s1 = sums[4 * t] + sums[4 * t + 1] + sums[4 * t + 2] + sums[4 * t + 3];
        float s2 = sums2[4 * t] + sums2[4 * t + 1] + sums2[4 * t + 2] + sums2[4 * t + 3];
        float mean = s1 * (1.f / 64.f);
        float var = s2 * (1.f / 64.f) - mean * mean;
        stat_m[t] = mean;
        stat_r[t] = rsqrtf(fmaxf(var, 0.f) + 1e-5f);
    }
    __syncthreads();
    for (int idx = t; idx < 4096; idx += 256) {
        int e = idx >> 6, j = idx & 63;
        float v = (h1f[e * 68 + j] - stat_m[e]) * stat_r[e] * g[j] + bt[j];
        h1b[e * 72 + j] = bfbits(v);
    }
    __syncthreads();   // h1b ready; h1f dead

    // ---- GEMM 2 into registers (h1b stays read-only) ----
    f32x4 acc2[4];
    #pragma unroll
    for (int m = 0; m < 4; ++m) {
        f32x4 acc = {0.f, 0.f, 0.f, 0.f};
        #pragma unroll
        for (int kk = 0; kk < 2; ++kk) {
            bfrag8 a = *(const bfrag8*)&h1b[(m * 16 + lm) * 72 + kk * 32 + qd * 8];
            acc = __builtin_amdgcn_mfma_f32_16x16x32_bf16(a, w2f[kk], acc, 0, 0, 0);
        }
        acc2[m] = acc;
    }
    __syncthreads();   // all h1b reads done -> msgb alias live
    #pragma unroll
    for (int m = 0; m < 4; ++m)
        #pragma unroll
        for (int r = 0; r < 4; ++r) {
            int mr = m * 16 + qd * 4 + r;
            float v = acc2[m][r] + b2n;
            msgf[mr * 68 + n] = v;
            msgb[mr * 72 + n] = bfbits(v);
        }
    __syncthreads();

    // ---- run-aggregated aggr atomics ----
    {
        int j = t & 63, q = t >> 6;
        float acc = 0.f;
        #pragma unroll
        for (int e = q * 16; e < q * 16 + 16; ++e) {
            acc += msgf[e * 68 + j];
            bool flush = (e - q * 16 == 15) || (dsts[e + 1] != dsts[e]);
            if (flush) {
                atomicAdd(&aggr[(size_t)dsts[e] * 64 + j], acc);
                acc = 0.f;
            }
        }
    }

    // ---- GEMM 3: bf16 A-frags straight from msgb ----
    #pragma unroll
    for (int m = 0; m < 4; ++m) {
        f32x4 acc = {0.f, 0.f, 0.f, 0.f};
        #pragma unroll
        for (int kk = 0; kk < 2; ++kk) {
            bfrag8 a = *(const bfrag8*)&msgb[(m * 16 + lm) * 72 + kk * 32 + qd * 8];
            acc = __builtin_amdgcn_mfma_f32_16x16x32_bf16(a, c1f[kk], acc, 0, 0, 0);
        }
        #pragma unroll
        for (int r = 0; r < 4; ++r) {
            float v = acc[r] + cb1n;
            v = v > 0.f ? v : 0.01f * v;
            v *= cw2n;
            v += __shfl_xor(v, 1);
            v += __shfl_xor(v, 2);
            v += __shfl_xor(v, 4);
            v += __shfl_xor(v, 8);
            if (lm == 0) coefp[wv][m * 16 + qd * 4 + r] = v;
        }
    }
    __syncthreads();
    if (t < 64)
        coef_all[t] = coefp[0][t] + coefp[1][t] + coefp[2][t] + coefp[3][t] + cb2[0];
    __syncthreads();

    if (t < 12) {
        int q = t / 3, ax = t - q * 3;
        float acc = 0.f;
        for (int e = q * 16; e < q * 16 + 16; ++e) {
            acc += xr_s[e][ax] * coef_all[e];
            bool flush = (e - q * 16 == 15) || (dsts[e + 1] != dsts[e]);
            if (flush) {
                atomicAdd(&xacc[dsts[e] * 3 + ax], acc);
                acc = 0.f;
            }
        }
    }
}

// ============ MFMA node kernel: 64 nodes/block ============
__global__ __launch_bounds__(256, 3) void node_mfma(
    const float* h, const float* __restrict__ aggr,
    const int* __restrict__ cnt, const float* att,   // att aliases h_out
    const float* __restrict__ orig_h,
    const float* __restrict__ w1, const float* __restrict__ b1,
    const float* __restrict__ g, const float* __restrict__ bt,
    const float* __restrict__ w2, const float* __restrict__ b2,
    float* h_out)
{
    constexpr int KP = 264;   // 256 + 8 pad (bf16)
    __shared__ __align__(16) char smem[64 * KP * 2];   // 33.8 KB; f32 alias fits (17.4)
    __shared__ __align__(16) unsigned short h1b[64 * 72];
    __shared__ float sums[256], sums2[256];
    __shared__ float stat_m[64], stat_r[64];
    unsigned short* xb  = (unsigned short*)smem;
    float*          h1f = (float*)smem;

    const int t  = threadIdx.x;
    const int wv = t >> 6;
    const int L  = t & 63;
    const int lm = L & 15;
    const int qd = L >> 4;
    const int n0 = blockIdx.x * 64;
    const int n  = wv * 16 + lm;

    bfrag8 w1f[8], w2f[2];
    #pragma unroll
    for (int kk = 0; kk < 8; ++kk)
        #pragma unroll
        for (int j = 0; j < 8; ++j) {
            int k = kk * 32 + qd * 8 + j;
            w1f[kk][j] = bfbits(w1[k * 64 + n]);
        }
    #pragma unroll
    for (int kk = 0; kk < 2; ++kk)
        #pragma unroll
        for (int j = 0; j < 8; ++j) {
            int k = kk * 32 + qd * 8 + j;
            w2f[kk][j] = bfbits(w2[k * 64 + n]);
        }
    const float b1n = b1[n], b2n = b2[n];

    for (int p = 0; p < 16; ++p) {
        int e = (t >> 6) + 4 * p;
        int node = n0 + e;
        float invc = 1.f / fmaxf((float)cnt[node], 1.f);
        int j = t & 63;
        xb[e * KP + j]       = bfbits(h[(size_t)node * 64 + j]);
        xb[e * KP + 64 + j]  = bfbits(aggr[(size_t)node * 64 + j] * invc);
        xb[e * KP + 128 + j] = bfbits(att[(size_t)node * 64 + j]);
        xb[e * KP + 192 + j] = bfbits(orig_h[(size_t)node * 64 + j]);
    }
    __syncthreads();

    f32x4 acc1[4];
    #pragma unroll
    for (int m = 0; m < 4; ++m) {
        f32x4 acc = {0.f, 0.f, 0.f, 0.f};
        #pragma unroll
        for (int kk = 0; kk < 8; ++kk) {
            bfrag8 a = *(const bfrag8*)&xb[(m * 16 + lm) * KP + kk * 32 + qd * 8];
            acc = __builtin_amdgcn_mfma_f32_16x16x32_bf16(a, w1f[kk], acc, 0, 0, 0);
        }
        acc1[m] = acc;
    }
    __syncthreads();
    #pragma unroll
    for (int m = 0; m < 4; ++m)
        #pragma unroll
        for (int r = 0; r < 4; ++r) {
            int mr = m * 16 + qd * 4 + r;
            float v = acc1[m][r] + b1n;
            v = v > 0.f ? v : 0.01f * v;
            h1f[mr * 68 + n] = v;
        }
    __syncthreads();

    {
        int e = t >> 2, seg = (t & 3) * 16;
        float s1 = 0.f, s2 = 0.f;
        #pragma unroll
        for (int j = 0; j < 16; ++j) {
            float v = h1f[e * 68 + seg + j];
            s1 += v; s2 += v * v;
        }
        sums[t] = s1; sums2[t] = s2;
    }
    __syncthreads();
    if (t < 64) {
        float s1 = sums[4 * t] + sums[4 * t + 1] + sums[4 * t + 2] + sums[4 * t + 3];
        float s2 = sums2[4 * t] + sums2[4 * t + 1] + sums2[4 * t + 2] + sums2[4 * t + 3];
        float mean = s1 * (1.f / 64.f);
        float var = s2 * (1.f / 64.f) - mean * mean;
        stat_m[t] = mean;
        stat_r[t] = rsqrtf(fmaxf(var, 0.f) + 1e-5f);
    }
    __syncthreads();
    for (int idx = t; idx < 4096; idx += 256) {
        int e = idx >> 6, j = idx & 63;
        float v = (h1f[e * 68 + j] - stat_m[e]) * stat_r[e] * g[j] + bt[j];
        h1b[e * 72 + j] = bfbits(v);
    }
    __syncthreads();

    #pragma unroll
    for (int m = 0; m < 4; ++m) {
        f32x4 acc = {0.f, 0.f, 0.f, 0.f};
        #pragma unroll
        for (int kk = 0; kk < 2; ++kk) {
            bfrag8 a = *(const bfrag8*)&h1b[(m * 16 + lm) * 72 + kk * 32 + qd * 8];
            acc = __builtin_amdgcn_mfma_f32_16x16x32_bf16(a, w2f[kk], acc, 0, 0, 0);
        }
        #pragma unroll
        for (int r = 0; r < 4; ++r) {
            int row = n0 + m * 16 + qd * 4 + r;
            float o = acc[r] + b2n;
            float hv = h[(size_t)row * 64 + n];
            h_out[(size_t)row * 64 + n] = 0.5f * o + 0.5f * hv;
        }
    }
}

// ---------------- k/v projection (bf16 out) ----------------
__global__ __launch_bounds__(64) void linear64_kernel(
    const float* __restrict__ h, const float* __restrict__ w,
    bf16* __restrict__ out, int do_lrelu)
{
    int node = blockIdx.x;
    int j = threadIdx.x;
    __shared__ float x[64];
    x[j] = h[(size_t)node * 64 + j];
    __syncthreads();
    float acc = 0.f;
    #pragma unroll 8
    for (int i = 0; i < 64; ++i) acc += x[i] * w[i * 64 + j];
    if (do_lrelu) acc = acc > 0.f ? acc : 0.01f * acc;
    out[(size_t)node * 64 + j] = __float2bfloat16(acc);
}

// ---------------- u8 mask build ----------------
__global__ __launch_bounds__(256) void build_masks(
    const float* __restrict__ mask, unsigned char* __restrict__ m8,
    unsigned char* __restrict__ m8T, int R, int C)
{
    __shared__ __align__(16) unsigned char tl[64 * 80];
    int r0 = blockIdx.y * 64, c0 = blockIdx.x * 64;
    int t = threadIdx.x;
    int cs = (t & 15) * 4;
    #pragma unroll
    for (int rr = 0; rr < 4; ++rr) {
        int r = (t >> 4) + rr * 16;
        unsigned b0 = (mask[(size_t)(r0 + r) * C + c0 + cs + 0] != 0.f);
        unsigned b1 = (mask[(size_t)(r0 + r) * C + c0 + cs + 1] != 0.f);
        unsigned b2 = (mask[(size_t)(r0 + r) * C + c0 + cs + 2] != 0.f);
        unsigned b3 = (mask[(size_t)(r0 + r) * C + c0 + cs + 3] != 0.f);
        *(unsigned*)&m8[(size_t)(r0 + r) * C + c0 + cs] = b0 | (b1 << 8) | (b2 << 16) | (b3 << 24);
        tl[(cs + 0) * 80 + r] = (unsigned char)b0;
        tl[(cs + 1) * 80 + r] = (unsigned char)b1;
        tl[(cs + 2) * 80 + r] = (unsigned char)b2;
        tl[(cs + 3) * 80 + r] = (unsigned char)b3;
    }
    __syncthreads();
    {
        int c = t >> 2, rs = (t & 3) * 16;
        *(uint4*)&m8T[(size_t)(c0 + c) * R + r0 + rs] = *(const uint4*)&tl[c * 80 + rs];
    }
}

// ============ MFMA flash attention (unchanged, verified) ============
template <int MMODE>
__global__ __launch_bounds__(256) void attn_mfma(
    int nb1,
    const float* __restrict__ h1, const float* __restrict__ qw1,
    const bf16* __restrict__ k1, const bf16* __restrict__ v1,
    const unsigned char* __restrict__ m81, const float* __restrict__ mf1, long mrs1, long mcs1,
    float* __restrict__ pO1, float* __restrict__ pM1, float* __restrict__ pL1,
    int nrows1, int ncols1, int nsplit1,
    const float* __restrict__ h2, const float* __restrict__ qw2,
    const bf16* __restrict__ k2, const bf16* __restrict__ v2,
    const unsigned char* __restrict__ m82, const float* __restrict__ mf2, long mrs2, long mcs2,
    float* __restrict__ pO2, float* __restrict__ pM2, float* __restrict__ pL2,
    int nrows2, int ncols2, int nsplit2)
{
    const float *h, *qw, *mf;
    const bf16 *kkp, *vvp;
    const unsigned char* m8;
    long mrs, mcs;
    float *pO, *pM, *pL;
    int n_rows, n_cols, nsplit, bid;
    if ((int)blockIdx.x < nb1) {
        h = h1; qw = qw1; kkp = k1; vvp = v1; m8 = m81; mf = mf1; mrs = mrs1; mcs = mcs1;
        pO = pO1; pM = pM1; pL = pL1; n_rows = nrows1; n_cols = ncols1; nsplit = nsplit1;
        bid = blockIdx.x;
    } else {
        h = h2; qw = qw2; kkp = k2; vvp = v2; m8 = m82; mf = mf2; mrs = mrs2; mcs = mcs2;
        pO = pO2; pM = pM2; pL = pL2; n_rows = nrows2; n_cols = ncols2; nsplit = nsplit2;
        bid = blockIdx.x - nb1;
    }

    const int t  = threadIdx.x;
    const int wv = t >> 6;
    const int lm = t & 15;
    const int qd = (t & 63) >> 4;
    const int rb = bid / nsplit;
    const int sp = bid - rb * nsplit;
    const int r0 = rb * 64;
    const int cols_per = n_cols / nsplit;
    const int c_begin = sp * cols_per;

    __shared__ __align__(16) unsigned short qb[64 * 72];
    __shared__ __align__(16) unsigned short kvb[64 * 72];
    __shared__ __align__(16) unsigned short pb[64 * 72];
    __shared__ __align__(16) unsigned char mt[4096];

    {
        int r = t >> 3, seg = (t & 7) * 8;
        #pragma unroll
        for (int u = 0; u < 2; ++u) {
            int rr = r + 32 * u;
            const float* hp = h + (size_t)(r0 + rr) * 64 + seg;
            unsigned short tmp[8];
            #pragma unroll
            for (int j = 0; j < 8; ++j) tmp[j] = bfbits(hp[j]);
            *(uint4*)&qb[rr * 72 + seg] = *(uint4*)tmp;
            const float* qp = qw + (size_t)rr * 64 + seg;
            #pragma unroll
            for (int j = 0; j < 8; ++j) kvb[(seg + j) * 72 + rr] = bfbits(qp[j]);
        }
    }
    __syncthreads();
    {
        bfrag8 a0 = *(const bfrag8*)&qb[(wv * 16 + lm) * 72 + qd * 8];
        bfrag8 a1 = *(const bfrag8*)&qb[(wv * 16 + lm) * 72 + 32 + qd * 8];
        #pragma unroll
        for (int ns = 0; ns < 4; ++ns) {
            f32x4 acc = {0.f, 0.f, 0.f, 0.f};
            bfrag8 b0 = *(const bfrag8*)&kvb[(ns * 16 + lm) * 72 + qd * 8];
            bfrag8 b1 = *(const bfrag8*)&kvb[(ns * 16 + lm) * 72 + 32 + qd * 8];
            acc = __builtin_amdgcn_mfma_f32_16x16x32_bf16(a0, b0, acc, 0, 0, 0);
            acc = __builtin_amdgcn_mfma_f32_16x16x32_bf16(a1, b1, acc, 0, 0, 0);
            #pragma unroll
            for (int r = 0; r < 4; ++r) {
                float v = acc[r];
                v = v > 0.f ? v : 0.01f * v;
                pb[(wv * 16 + qd * 4 + r) * 72 + ns * 16 + lm] = bfbits(v);
            }
        }
    }
    __syncthreads();
    for (int idx = t; idx < 64 * 9; idx += 256) {
        int r = idx / 9, seg = (idx - r * 9) * 8;
        if (seg < 64) *(uint4*)&qb[r * 72 + seg] = *(const uint4*)&pb[r * 72 + seg];
    }
    __syncthreads();

    float rm[4], rl[4];
    #pragma unroll
    for (int r = 0; r < 4; ++r) { rm[r] = -1e30f; rl[r] = 0.f; }
    f32x4 o[4];
    #pragma unroll
    for (int ds = 0; ds < 4; ++ds) o[ds] = (f32x4){0.f, 0.f, 0.f, 0.f};

    for (int c0 = c_begin; c0 < c_begin + cols_per; c0 += 64) {
        {
            int c = t >> 3, seg = (t & 7) * 8;
            #pragma unroll
            for (int u = 0; u < 2; ++u) {
                int cc = c + 32 * u;
                *(uint4*)&kvb[cc * 72 + seg] =
                    *(const uint4*)(kkp + (size_t)(c0 + cc) * 64 + seg);
            }
        }
        if (MMODE == 0) {
            int r = t >> 2, seg = (t & 3) * 16;
            *(uint4*)&mt[r * 64 + seg] =
                *(const uint4*)&m8[(size_t)(r0 + r) * n_cols + c0 + seg];
        } else {
            #pragma unroll
            for (int u = 0; u < 16; ++u) {
                int i = t + 256 * u;
                int r = i >> 6, c = i & 63;
                mt[r * 64 + c] = (unsigned char)(
                    mf[(size_t)(r0 + r) * mrs + (size_t)(c0 + c) * mcs] != 0.f);
            }
        }
        __syncthreads();

        f32x4 s[4];
        {
            bfrag8 a0 = *(const bfrag8*)&qb[(wv * 16 + lm) * 72 + qd * 8];
            bfrag8 a1 = *(const bfrag8*)&qb[(wv * 16 + lm) * 72 + 32 + qd * 8];
            #pragma unroll
            for (int ns = 0; ns < 4; ++ns) {
                f32x4 acc = {0.f, 0.f, 0.f, 0.f};
                bfrag8 b0 = *(const bfrag8*)&kvb[(ns * 16 + lm) * 72 + qd * 8];
                bfrag8 b1 = *(const bfrag8*)&kvb[(ns * 16 + lm) * 72 + 32 + qd * 8];
                acc = __builtin_amdgcn_mfma_f32_16x16x32_bf16(a0, b0, acc, 0, 0, 0);
                acc = __builtin_amdgcn_mfma_f32_16x16x32_bf16(a1, b1, acc, 0, 0, 0);
                s[ns] = acc;
            }
        }
        float alpha[4];
        #pragma unroll
        for (int r = 0; r < 4; ++r) {
            int rloc = wv * 16 + qd * 4 + r;
            float v0 = mt[rloc * 64 +  0 + lm] ? s[0][r] : -1000.f;
            float v1 = mt[rloc * 64 + 16 + lm] ? s[1][r] : -1000.f;
            float v2 = mt[rloc * 64 + 32 + lm] ? s[2][r] : -1000.f;
            float v3 = mt[rloc * 64 + 48 + lm] ? s[3][r] : -1000.f;
            float mx = quad_max(fmaxf(fmaxf(v0, v1), fmaxf(v2, v3)));
            float mn = fmaxf(rm[r], mx);
            float al = __expf(rm[r] - mn);
            rm[r] = mn; alpha[r] = al;
            float p0 = __expf(v0 - mn), p1 = __expf(v1 - mn);
            float p2 = __expf(v2 - mn), p3 = __expf(v3 - mn);
            pb[rloc * 72 +  0 + lm] = bfbits(p0);
            pb[rloc * 72 + 16 + lm] = bfbits(p1);
            pb[rloc * 72 + 32 + lm] = bfbits(p2);
            pb[rloc * 72 + 48 + lm] = bfbits(p3);
            float ls = quad_sum(p0 + p1 + p2 + p3);
            rl[r] = rl[r] * al + ls;
        }
        #pragma unroll
        for (int ds = 0; ds < 4; ++ds)
            #pragma unroll
            for (int r = 0; r < 4; ++r) o[ds][r] *= alpha[r];
        __syncthreads();

        {
            int c = t >> 3, seg = (t & 7) * 8;
            #pragma unroll
            for (int u = 0; u < 2; ++u) {
                int cc = c + 32 * u;
                uint4 raw = *(const uint4*)(vvp + (size_t)(c0 + cc) * 64 + seg);
                unsigned short* pr = (unsigned short*)&raw;
                #pragma unroll
                for (int j = 0; j < 8; ++j) kvb[(seg + j) * 72 + cc] = pr[j];
            }
        }
        __syncthreads();

        {
            bfrag8 a0 = *(const bfrag8*)&pb[(wv * 16 + lm) * 72 + qd * 8];
            bfrag8 a1 = *(const bfrag8*)&pb[(wv * 16 + lm) * 72 + 32 + qd * 8];
            #pragma unroll
            for (int ds = 0; ds < 4; ++ds) {
                bfrag8 b0 = *(const bfrag8*)&kvb[(ds * 16 + lm) * 72 + qd * 8];
                bfrag8 b1 = *(const bfrag8*)&kvb[(ds * 16 + lm) * 72 + 32 + qd * 8];
                o[ds] = __builtin_amdgcn_mfma_f32_16x16x32_bf16(a0, b0, o[ds], 0, 0, 0);
                o[ds] = __builtin_amdgcn_mfma_f32_16x16x32_bf16(a1, b1, o[ds], 0, 0, 0);
            }
        }
        __syncthreads();
    }

    #pragma unroll
    for (int ds = 0; ds < 4; ++ds)
        #pragma unroll
        for (int r = 0; r < 4; ++r) {
            int row = r0 + wv * 16 + qd * 4 + r;
            pO[((size_t)sp * n_rows + row) * 64 + ds * 16 + lm] = o[ds][r];
        }
    if (lm == 0) {
        #pragma unroll
        for (int r = 0; r < 4; ++r) {
            int row = r0 + wv * 16 + qd * 4 + r;
            pM[(size_t)sp * n_rows + row] = rm[r];
            pL[(size_t)sp * n_rows + row] = rl[r];
        }
    }
}

// ---------------- merge split partials ----------------
__global__ __launch_bounds__(64) void attn_merge(
    const float* __restrict__ pO, const float* __restrict__ pM, const float* __restrict__ pL,
    float* __restrict__ out, int n_rows, int nsplit)
{
    int r = blockIdx.x;
    int d = threadIdx.x;
    float mstar = -1e30f;
    for (int s = 0; s < nsplit; ++s) mstar = fmaxf(mstar, pM[(size_t)s * n_rows + r]);
    float L = 0.f, O = 0.f;
    for (int s = 0; s < nsplit; ++s) {
        float w = __expf(pM[(size_t)s * n_rows + r] - mstar);
        L += pL[(size_t)s * n_rows + r] * w;
        O += pO[((size_t)s * n_rows + r) * 64 + d] * w;
    }
    out[(size_t)r * 64 + d] = O / L;
}

// ---------------- per-row attention (tier-2 fallback) ----------------
__global__ __launch_bounds__(256) void attn_row_kernel(
    const float* __restrict__ h, const float* __restrict__ qw,
    const bf16* __restrict__ k, const bf16* __restrict__ v,
    const float* __restrict__ mask, long mrs, long mcs,
    float* __restrict__ out, int n_cols)
{
    int row = blockIdx.x;
    int tid = threadIdx.x;
    extern __shared__ float sc[];
    __shared__ float hrow[64];
    __shared__ float qrow[64];
    __shared__ float red[4];
    __shared__ float opart[4][64];

    if (tid < 64) hrow[tid] = h[(size_t)row * 64 + tid];
    __syncthreads();
    if (tid < 64) {
        float a = 0.f;
        #pragma unroll 8
        for (int i = 0; i < 64; ++i) a += hrow[i] * qw[i * 64 + tid];
        qrow[tid] = a > 0.f ? a : 0.01f * a;
    }
    __syncthreads();

    float lmax = -1e30f;
    for (int c = tid; c < n_cols; c += 256) {
        const bf16* kr = k + (size_t)c * 64;
        float s = 0.f;
        #pragma unroll 8
        for (int i = 0; i < 64; ++i) s += qrow[i] * ldkv(kr, i);
        float m = mask[(size_t)row * mrs + (size_t)c * mcs];
        s = m * s - 1000.f * (1.f - m);
        sc[c] = s;
        lmax = fmaxf(lmax, s);
    }
    #pragma unroll
    for (int o = 32; o > 0; o >>= 1) lmax = fmaxf(lmax, __shfl_xor(lmax, o, 64));
    int wid = tid >> 6;
    if ((tid & 63) == 0) red[wid] = lmax;
    __syncthreads();
    float bmax = fmaxf(fmaxf(red[0], red[1]), fmaxf(red[2], red[3]));
    __syncthreads();

    float lsum = 0.f;
    for (int c = tid; c < n_cols; c += 256) {
        float e = __expf(sc[c] - bmax);
        sc[c] = e;
        lsum += e;
    }
    lsum = wave_sum(lsum);
    if ((tid & 63) == 0) red[wid] = lsum;
    __syncthreads();
    float inv = 1.f / (red[0] + red[1] + red[2] + red[3]);

    int dd = tid & 63;
    float o = 0.f;
    for (int c = wid; c < n_cols; c += 4) o += sc[c] * ldkv(v, (size_t)c * 64 + dd);
    opart[wid][dd] = o;
    __syncthreads();
    if (wid == 0)
        out[(size_t)row * 64 + dd] =
            (opart[0][dd] + opart[1][dd] + opart[2][dd] + opart[3][dd]) * inv;
}

// ---------------- coordinate output ----------------
__global__ void coord_kernel(
    const float* __restrict__ orig, const float* __restrict__ coords,
    const float* __restrict__ xacc, const int* __restrict__ cnt,
    float* __restrict__ out, int n3)
{
    int i = blockIdx.x * blockDim.x + threadIdx.x;
    if (i >= n3) return;
    int node = i / 3;
    float invc = 1.f / fmaxf((float)cnt[node], 1.f);
    out[i] = 0.25f * orig[i] + 0.75f * coords[i] + xacc[i] * invc;
}

extern "C" void kernel_launch(void* const* d_in, const int* in_sizes, int n_in,
                              void* d_out, int out_size, void* d_ws, size_t ws_size,
                              hipStream_t stream)
{
    const float* coords_lig      = (const float*)d_in[0];
    const float* h_lig           = (const float*)d_in[1];
    const float* orig_h_lig      = (const float*)d_in[2];
    const float* orig_coords_lig = (const float*)d_in[3];
    const float* coords_rec      = (const float*)d_in[4];
    const float* h_rec           = (const float*)d_in[5];
    const float* orig_h_rec      = (const float*)d_in[6];
    const float* orig_coords_rec = (const float*)d_in[7];
    const int* lig_src   = (const int*)d_in[8];
    const int* lig_dst   = (const int*)d_in[9];
    const float* lig_efeat = (const float*)d_in[10];
    const int* rec_src   = (const int*)d_in[11];
    const int* rec_dst   = (const int*)d_in[12];
    const float* rec_efeat = (const float*)d_in[13];
    const float* mask      = (const float*)d_in[14];
    const float *lig_em_w1 = (const float*)d_in[15], *lig_em_b1 = (const float*)d_in[16];
    const float *lig_em_g  = (const float*)d_in[17], *lig_em_bt = (const float*)d_in[18];
    const float *lig_em_w2 = (const float*)d_in[19], *lig_em_b2 = (const float*)d_in[20];
    const float *rec_em_w1 = (const float*)d_in[21], *rec_em_b1 = (const float*)d_in[22];
    const float *rec_em_g  = (const float*)d_in[23], *rec_em_bt = (const float*)d_in[24];
    const float *rec_em_w2 = (const float*)d_in[25], *rec_em_b2 = (const float*)d_in[26];
    const float *lig_cm_w1 = (const float*)d_in[27], *lig_cm_b1 = (const float*)d_in[28];
    const float *lig_cm_w2 = (const float*)d_in[29], *lig_cm_b2 = (const float*)d_in[30];
    const float *rec_cm_w1 = (const float*)d_in[31], *rec_cm_b1 = (const float*)d_in[32];
    const float *rec_cm_w2 = (const float*)d_in[33], *rec_cm_b2 = (const float*)d_in[34];
    const float *q_lig_w = (const float*)d_in[35], *k_lig_w = (const float*)d_in[36];
    const float *v_lig_w = (const float*)d_in[37], *q_rec_w = (const float*)d_in[38];
    const float *k_rec_w = (const float*)d_in[39], *v_rec_w = (const float*)d_in[40];
    const float *lig_nm_w1 = (const float*)d_in[41], *lig_nm_b1 = (const float*)d_in[42];
    const float *lig_nm_g  = (const float*)d_in[43], *lig_nm_bt = (const float*)d_in[44];
    const float *lig_nm_w2 = (const float*)d_in[45], *lig_nm_b2 = (const float*)d_in[46];
    const float *rec_nm_w1 = (const float*)d_in[47], *rec_nm_b1 = (const float*)d_in[48];
    const float *rec_nm_g  = (const float*)d_in[49], *rec_nm_bt = (const float*)d_in[50];
    const float *rec_nm_w2 = (const float*)d_in[51], *rec_nm_b2 = (const float*)d_in[52];

    char* wsb = (char*)d_ws;
    float* aggr_l = (float*)(wsb + 16);
    float* aggr_r = aggr_l + (size_t)N_LIG * 64;
    float* xacc_l = aggr_r + (size_t)N_REC * 64;
    float* xacc_r = xacc_l + (size_t)N_LIG * 3;
    int* counts_l = (int*)(xacc_r + (size_t)N_REC * 3);
    int* counts_r = counts_l + N_LIG;
    const size_t zero_floats =
        (size_t)N_LIG * 64 + (size_t)N_REC * 64 + N_LIG * 3 + N_REC * 3 + N_LIG + N_REC;
    int* cursor_l = counts_r + N_REC;
    int* cursor_r = cursor_l + N_LIG;
    int* order_l  = cursor_r + N_REC;
    int* order_r  = order_l + E_LIG;
    char* kv_base = (char*)(order_r + E_REC);
    const size_t core_b = (size_t)(kv_base - wsb);
    const size_t kv_b = (size_t)(N_LIG + N_REC) * 64 * 2 * 2;
    const size_t part_b = ((size_t)4 * N_LIG * 64 + (size_t)2 * N_REC * 64) * 4
                        + ((size_t)4 * N_LIG + (size_t)2 * N_REC) * 2 * 4;
    const size_t m8_b = (size_t)N_LIG * N_REC;

    int tier;
    if (ws_size >= core_b + kv_b + part_b + 2 * m8_b) tier = 0;
    else if (ws_size >= core_b + kv_b + part_b) tier = 1;
    else tier = 2;

    bf16* kb_l = (bf16*)kv_base;
    bf16* vb_l = kb_l + (size_t)N_LIG * 64;
    bf16* kb_r = vb_l + (size_t)N_LIG * 64;
    bf16* vb_r = kb_r + (size_t)N_REC * 64;
    float* pO1 = (float*)(kv_base + kv_b);
    float* pO2 = pO1 + (size_t)4 * N_LIG * 64;
    float* pM1 = pO2 + (size_t)2 * N_REC * 64;
    float* pL1 = pM1 + (size_t)4 * N_LIG;
    float* pM2 = pL1 + (size_t)4 * N_LIG;
    float* pL2 = pM2 + (size_t)2 * N_REC;
    unsigned char* m8  = (unsigned char*)(kv_base + kv_b + part_b);
    unsigned char* m8T = m8 + m8_b;
    // bf16 input mirrors, aliasing m8 region (consumed by edge kernels before
    // build_masks overwrites — stream-serialized, graph-stable)
    bf16* hb_l  = (bf16*)m8;
    bf16* hb_r  = hb_l + (size_t)N_LIG * 64;
    bf16* efb_l = hb_r + (size_t)N_REC * 64;
    bf16* efb_r = efb_l + (size_t)E_LIG * F_LIGc;

    float* out = (float*)d_out;
    float* x_lig_o = out;
    float* h_lig_o = out + 12288;
    float* x_rec_o = out + 274432;
    float* h_rec_o = out + 299008;

    zero_kernel<<<((int)zero_floats + 255) / 256, 256, 0, stream>>>(aggr_l, (int)zero_floats);

    // counting sort by dst
    hist_kernel<<<E_LIG / 256, 256, 0, stream>>>(lig_dst, counts_l, E_LIG);
    hist_kernel<<<E_REC / 256, 256, 0, stream>>>(rec_dst, counts_r, E_REC);
    scan_kernel<<<1, 256, 0, stream>>>(counts_l, cursor_l, N_LIG);
    scan_kernel<<<1, 256, 0, stream>>>(counts_r, cursor_r, N_REC);
    scatter_kernel<<<E_LIG / 256, 256, 0, stream>>>(lig_dst, cursor_l, order_l, E_LIG);
    scatter_kernel<<<E_REC / 256, 256, 0, stream>>>(rec_dst, cursor_r, order_r, E_REC);

    // k/v projections (bf16)
    linear64_kernel<<<N_LIG, 64, 0, stream>>>(h_lig, k_lig_w, kb_l, 1);
    linear64_kernel<<<N_LIG, 64, 0, stream>>>(h_lig, v_lig_w, vb_l, 0);
    linear64_kernel<<<N_REC, 64, 0, stream>>>(h_rec, k_rec_w, kb_r, 1);
    linear64_kernel<<<N_REC, 64, 0, stream>>>(h_rec, v_rec_w, vb_r, 0);

    // edge kernels (bf16 pre-converted inputs in tier0)
    if (tier == 0) {
        cvt_kernel<<<(N_LIG * 64 + 255) / 256, 256, 0, stream>>>(h_lig, hb_l, N_LIG * 64);
        cvt_kernel<<<(N_REC * 64 + 255) / 256, 256, 0, stream>>>(h_rec, hb_r, N_REC * 64);
        cvt_kernel<<<(E_LIG * F_LIGc + 255) / 256, 256, 0, stream>>>(lig_efeat, efb_l, E_LIG * F_LIGc);
        cvt_kernel<<<(E_REC * F_RECc + 255) / 256, 256, 0, stream>>>(rec_efeat, efb_r, E_REC * F_RECc);
        edge_mfma<F_LIGc, 5, bf16><<<E_LIG / 64, 256, 0, stream>>>(
            order_l, coords_lig, hb_l, lig_src, lig_dst, efb_l,
            lig_em_w1, lig_em_b1, lig_em_g, lig_em_bt, lig_em_w2, lig_em_b2,
            lig_cm_w1, lig_cm_b1, lig_cm_w2, lig_cm_b2,
            aggr_l, xacc_l);
        edge_mfma<F_RECc, 6, bf16><<<E_REC / 64, 256, 0, stream>>>(
            order_r, coords_rec, hb_r, rec_src, rec_dst, efb_r,
            rec_em_w1, rec_em_b1, rec_em_g, rec_em_bt, rec_em_w2, rec_em_b2,
            rec_cm_w1, rec_cm_b1, rec_cm_w2, rec_cm_b2,
            aggr_r, xacc_r);
    } else {
        edge_mfma<F_LIGc, 5, float><<<E_LIG / 64, 256, 0, stream>>>(
            order_l, coords_lig, h_lig, lig_src, lig_dst, lig_efeat,
            lig_em_w1, lig_em_b1, lig_em_g, lig_em_bt, lig_em_w2, lig_em_b2,
            lig_cm_w1, lig_cm_b1, lig_cm_w2, lig_cm_b2,
            aggr_l, xacc_l);
        edge_mfma<F_RECc, 6, float><<<E_REC / 64, 256, 0, stream>>>(
            order_r, coords_rec, h_rec, rec_src, rec_dst, rec_efeat,
            rec_em_w1, rec_em_b1, rec_em_g, rec_em_bt, rec_em_w2, rec_em_b2,
            rec_cm_w1, rec_cm_b1, rec_cm_w2, rec_cm_b2,
            aggr_r, xacc_r);
    }

    // attention
    const int nb1 = (N_LIG / 64) * 4;
    const int nb2 = (N_REC / 64) * 2;
    if (tier <= 1) {
        if (tier == 0) {
            dim3 bg(N_REC / 64, N_LIG / 64);
            build_masks<<<bg, 256, 0, stream>>>(mask, m8, m8T, N_LIG, N_REC);
            attn_mfma<0><<<nb1 + nb2, 256, 0, stream>>>(
                nb1,
                h_lig, q_lig_w, kb_r, vb_r, m8, mask, 0L, 0L,
                pO1, pM1, pL1, N_LIG, N_REC, 4,
                h_rec, q_rec_w, kb_l, vb_l, m8T, mask, 0L, 0L,
                pO2, pM2, pL2, N_REC, N_LIG, 2);
        } else {
            attn_mfma<1><<<nb1 + nb2, 256, 0, stream>>>(
                nb1,
                h_lig, q_lig_w, kb_r, vb_r, (const unsigned char*)0, mask, (long)N_REC, 1L,
                pO1, pM1, pL1, N_LIG, N_REC, 4,
                h_rec, q_rec_w, kb_l, vb_l, (const unsigned char*)0, mask, 1L, (long)N_REC,
                pO2, pM2, pL2, N_REC, N_LIG, 2);
        }
        attn_merge<<<N_LIG, 64, 0, stream>>>(pO1, pM1, pL1, h_lig_o, N_LIG, 4);
        attn_merge<<<N_REC, 64, 0, stream>>>(pO2, pM2, pL2, h_rec_o, N_REC, 2);
    } else {
        attn_row_kernel<<<N_LIG, 256, N_REC * sizeof(float), stream>>>(
            h_lig, q_lig_w, kb_r, vb_r, mask, (long)N_REC, 1L, h_lig_o, N_REC);
        attn_row_kernel<<<N_REC, 256, N_LIG * sizeof(float), stream>>>(
            h_rec, q_rec_w, kb_l, vb_l, mask, 1L, (long)N_REC, h_rec_o, N_LIG);
    }

    // node updates (MFMA, 64 nodes/block)
    node_mfma<<<N_LIG / 64, 256, 0, stream>>>(
        h_lig, aggr_l, counts_l, h_lig_o, orig_h_lig,
        lig_nm_w1, lig_nm_b1, lig_nm_g, lig_nm_bt, lig_nm_w2, lig_nm_b2, h_lig_o);
    node_mfma<<<N_REC / 64, 256, 0, stream>>>(
        h_rec, aggr_r, counts_r, h_rec_o, orig_h_rec,
        rec_nm_w1, rec_nm_b1, rec_nm_g, rec_nm_bt, rec_nm_w2, rec_nm_b2, h_rec_o);

    // coordinate outputs
    coord_kernel<<<(N_LIG * 3 + 255) / 256, 256, 0, stream>>>(
        orig_coords_lig, coords_lig, xacc_l, counts_l, x_lig_o, N_LIG * 3);
    coord_kernel<<<(N_REC * 3 + 255) / 256, 256, 0, stream>>>(
        orig_coords_rec, coords_rec, xacc_r, counts_r, x_rec_o, N_REC * 3);
}